// Round 1
// baseline (948.754 us; speedup 1.0000x reference)
//
#include <hip/hip_runtime.h>
#include <hip/hip_bf16.h>
#include <math.h>

#define TEMP 0.1

typedef float f4 __attribute__((ext_vector_type(4)));
typedef short s8v __attribute__((ext_vector_type(8)));
typedef int   i4v __attribute__((ext_vector_type(4)));

__device__ inline short f2bf(float f) {
    __hip_bfloat16 h = __float2bfloat16(f);
    return *reinterpret_cast<short*>(&h);
}
__device__ inline float bf2f(short s) {
    __hip_bfloat16 h = *reinterpret_cast<__hip_bfloat16*>(&s);
    return __bfloat162float(h);
}

// ---------- quantize rows of 1024 to 4 balanced int8 limbs (R6 code; numerics re-tested) ----------
// X = round(x * 2^sig), sig = 29 - ilogb(rowmax) => |X| < 2^30, top limb |d3| <= 64.
__global__ __launch_bounds__(256) void quantize_rows(
    const float* __restrict__ src, signed char* __restrict__ limbs,
    long plane_stride, double* __restrict__ scale)
{
    const int row = blockIdx.x, tid = threadIdx.x;
    const float4 v = ((const float4*)(src + (size_t)row * 1024))[tid];
    float m = fmaxf(fmaxf(fabsf(v.x), fabsf(v.y)), fmaxf(fabsf(v.z), fabsf(v.w)));
#pragma unroll
    for (int off = 32; off > 0; off >>= 1) m = fmaxf(m, __shfl_down(m, off));
    __shared__ float wmax[4];
    __shared__ int ssig;
    if ((tid & 63) == 0) wmax[tid >> 6] = m;
    __syncthreads();
    if (tid == 0) {
        float rm = fmaxf(fmaxf(wmax[0], wmax[1]), fmaxf(wmax[2], wmax[3]));
        int sig = (rm > 0.f) ? (29 - ilogbf(rm)) : 0;
        ssig = sig;
        scale[row] = ldexp(1.0, -sig);
    }
    __syncthreads();
    const double s2 = ldexp(1.0, ssig);
    float xs[4] = {v.x, v.y, v.z, v.w};
    signed char out[4][4];
#pragma unroll
    for (int e = 0; e < 4; ++e) {
        long X = __double2ll_rn((double)xs[e] * s2);
#pragma unroll
        for (int l = 0; l < 3; ++l) {
            int d = (int)(((X + 128) & 255) - 128);
            out[l][e] = (signed char)d;
            X = (X - d) >> 8;
        }
        out[3][e] = (signed char)X;
    }
#pragma unroll
    for (int l = 0; l < 4; ++l)
        *(char4*)&limbs[(size_t)l * plane_stride + (size_t)row * 1024 + tid * 4] =
            *(char4*)&out[l][0];
}

// ---------- fp32 -> bf16 hi/lo split planes (exactly the f2bf chain gemm_v64 used) ----------
__global__ __launch_bounds__(256) void tobf16_split(
    const float* __restrict__ src, short* __restrict__ hi, short* __restrict__ lo)
{
    const int row = blockIdx.x, tid = threadIdx.x;
    const float4 v = ((const float4*)(src + (size_t)row * 1024))[tid];
    float xs[4] = {v.x, v.y, v.z, v.w};
    __align__(8) short h[4], l[4];
#pragma unroll
    for (int e = 0; e < 4; ++e) {
        h[e] = f2bf(xs[e]);
        l[e] = f2bf(xs[e] - bf2f(h[e]));
    }
    *(short4*)&hi[(size_t)row * 1024 + tid * 4] = *(short4*)h;
    *(short4*)&lo[(size_t)row * 1024 + tid * 4] = *(short4*)l;
}

// ---------- exact i8-MFMA projection: 4 limb planes, 13 pairs (i+j>=2), 5 levels ----------
// LDS staging + register prefetch (R9-proven structure).
__global__ __launch_bounds__(256) void gemm_i8qk(
    const signed char* __restrict__ Xl,
    const signed char* __restrict__ Wql,
    const signed char* __restrict__ Wkl,
    const double* __restrict__ xsc,
    const double* __restrict__ wqsc, const double* __restrict__ wksc,
    const float* __restrict__ bq, const float* __restrict__ bk,
    double* __restrict__ Qd, double* __restrict__ Kd)
{
    const int K = 1024, N = 1024;
    const long MK = 2048L * 1024, NK = 1024L * 1024;
    const signed char* Wl = blockIdx.z ? Wkl : Wql;
    const double* wsc = blockIdx.z ? wksc : wqsc;
    const float* bias = blockIdx.z ? bk : bq;
    double* C = blockIdx.z ? Kd : Qd;

    __shared__ __align__(16) signed char Asm[4][64][80];
    __shared__ __align__(16) signed char Bsm[4][64][80];

    const int tid  = threadIdx.x;
    const int lane = tid & 63, wave = tid >> 6;
    const int wm = wave >> 1, wn = wave & 1;
    const int quad = lane >> 4, l16 = lane & 15;
    const int m0 = blockIdx.y * 64, n0 = blockIdx.x * 64;

    const int srow = tid >> 2, skq = (tid & 3) * 16;
    const signed char* ap = Xl + (size_t)(m0 + srow) * K + skq;
    const signed char* bp = Wl + (size_t)(n0 + srow) * K + skq;

    i4v acc[5][2][2] = {};   // level s = i+j-2

    i4v at[4], bt[4];
#pragma unroll
    for (int l = 0; l < 4; ++l) {
        at[l] = *(const i4v*)(ap + l * MK);
        bt[l] = *(const i4v*)(bp + l * NK);
    }

    for (int k0 = 0; k0 < K; k0 += 64) {
        __syncthreads();
#pragma unroll
        for (int l = 0; l < 4; ++l) {
            *(i4v*)&Asm[l][srow][skq] = at[l];
            *(i4v*)&Bsm[l][srow][skq] = bt[l];
        }
        __syncthreads();

        if (k0 + 64 < K) {
#pragma unroll
            for (int l = 0; l < 4; ++l) {
                at[l] = *(const i4v*)(ap + l * MK + k0 + 64);
                bt[l] = *(const i4v*)(bp + l * NK + k0 + 64);
            }
        }

        i4v bF[4][2];
#pragma unroll
        for (int j = 0; j < 4; ++j)
#pragma unroll
            for (int nt = 0; nt < 2; ++nt)
                bF[j][nt] = *(const i4v*)&Bsm[j][wn * 32 + nt * 16 + l16][quad * 16];

#pragma unroll
        for (int i = 0; i < 4; ++i) {
            i4v a0 = *(const i4v*)&Asm[i][wm * 32 +      l16][quad * 16];
            i4v a1 = *(const i4v*)&Asm[i][wm * 32 + 16 + l16][quad * 16];
#pragma unroll
            for (int j = 0; j < 4; ++j) {
                if (i + j < 2) continue;
                const int s = i + j - 2;
                acc[s][0][0] = __builtin_amdgcn_mfma_i32_16x16x64_i8(a0, bF[j][0], acc[s][0][0], 0, 0, 0);
                acc[s][0][1] = __builtin_amdgcn_mfma_i32_16x16x64_i8(a0, bF[j][1], acc[s][0][1], 0, 0, 0);
                acc[s][1][0] = __builtin_amdgcn_mfma_i32_16x16x64_i8(a1, bF[j][0], acc[s][1][0], 0, 0, 0);
                acc[s][1][1] = __builtin_amdgcn_mfma_i32_16x16x64_i8(a1, bF[j][1], acc[s][1][1], 0, 0, 0);
            }
        }
    }

    const double wt0 = ldexp(1.0, 16), wt1 = ldexp(1.0, 24), wt2 = ldexp(1.0, 32);
    const double wt3 = ldexp(1.0, 40), wt4 = ldexp(1.0, 48);
#pragma unroll
    for (int mt = 0; mt < 2; ++mt)
#pragma unroll
        for (int nt = 0; nt < 2; ++nt)
#pragma unroll
            for (int r = 0; r < 4; ++r) {
                int row = m0 + wm * 32 + mt * 16 + quad * 4 + r;
                int col = n0 + wn * 32 + nt * 16 + l16;
                double dsum = wt0 * (double)acc[0][mt][nt][r]
                            + wt1 * (double)acc[1][mt][nt][r]
                            + wt2 * (double)acc[2][mt][nt][r]
                            + wt3 * (double)acc[3][mt][nt][r]
                            + wt4 * (double)acc[4][mt][nt][r];
                C[(size_t)row * N + col] = dsum * xsc[row] * wsc[col] + (double)bias[col];
            }
}

// ------- V projection from precomputed bf16 hi/lo planes (bit-identical to R9 v64) -------
__global__ __launch_bounds__(256) void gemm_v64(
    const short* __restrict__ Ahp, const short* __restrict__ Alp,
    const short* __restrict__ Bhp, const short* __restrict__ Blp,
    const float* __restrict__ bias, float* __restrict__ C)
{
    const int K = 1024, N = 1024;
    __shared__ short Ah[64][40];
    __shared__ short Al[64][40];
    __shared__ short Bh[64][40];
    __shared__ short Bl[64][40];

    const int tid = threadIdx.x, lane = tid & 63, wave = tid >> 6;
    const int wm = wave >> 1, wn = wave & 1;
    const int quad = lane >> 4, l16 = lane & 15;
    const int m0 = blockIdx.y * 64, n0 = blockIdx.x * 64;
    const int srow = tid >> 2, sco = (tid & 3) * 8;
    const size_t aoff = (size_t)(m0 + srow) * K + sco;
    const size_t boff = (size_t)(n0 + srow) * K + sco;

    f4 acc[2][2] = {};
    for (int k0 = 0; k0 < K; k0 += 32) {
        s8v ah = *(const s8v*)(Ahp + aoff + k0);
        s8v al = *(const s8v*)(Alp + aoff + k0);
        s8v bh = *(const s8v*)(Bhp + boff + k0);
        s8v bl = *(const s8v*)(Blp + boff + k0);
        __syncthreads();
        *(s8v*)&Ah[srow][sco] = ah;
        *(s8v*)&Al[srow][sco] = al;
        *(s8v*)&Bh[srow][sco] = bh;
        *(s8v*)&Bl[srow][sco] = bl;
        __syncthreads();

        s8v af[2], afl[2], bf[2], bfl[2];
#pragma unroll
        for (int t = 0; t < 2; ++t) {
            af[t]  = *(s8v*)&Ah[wm * 32 + t * 16 + l16][quad * 8];
            afl[t] = *(s8v*)&Al[wm * 32 + t * 16 + l16][quad * 8];
            bf[t]  = *(s8v*)&Bh[wn * 32 + t * 16 + l16][quad * 8];
            bfl[t] = *(s8v*)&Bl[wn * 32 + t * 16 + l16][quad * 8];
        }
#pragma unroll
        for (int mt = 0; mt < 2; ++mt)
#pragma unroll
            for (int nt = 0; nt < 2; ++nt) {
                acc[mt][nt] = __builtin_amdgcn_mfma_f32_16x16x32_bf16(af[mt],  bf[nt],  acc[mt][nt], 0, 0, 0);
                acc[mt][nt] = __builtin_amdgcn_mfma_f32_16x16x32_bf16(af[mt],  bfl[nt], acc[mt][nt], 0, 0, 0);
                acc[mt][nt] = __builtin_amdgcn_mfma_f32_16x16x32_bf16(afl[mt], bf[nt],  acc[mt][nt], 0, 0, 0);
            }
    }
#pragma unroll
    for (int mt = 0; mt < 2; ++mt)
#pragma unroll
        for (int nt = 0; nt < 2; ++nt)
#pragma unroll
            for (int r = 0; r < 4; ++r) {
                int row = m0 + wm * 32 + mt * 16 + quad * 4 + r;
                int col = n0 + wn * 32 + nt * 16 + l16;
                C[(size_t)row * N + col] = acc[mt][nt][r] + bias[col];
            }
}

// ------- score GEMM: 64x64 tile, bf16 inputs, fp32 out (R8-proven) -------
__global__ __launch_bounds__(256) void gemm_score(
    const short* __restrict__ Qh, const short* __restrict__ Kh,
    float* __restrict__ C)
{
    const int K = 1024, N = 2048;
    __shared__ short As[64][40];
    __shared__ short Bs[64][40];
    const int tid = threadIdx.x, lane = tid & 63, wave = tid >> 6;
    const int wm = wave >> 1, wn = wave & 1;
    const int quad = lane >> 4, l16 = lane & 15;
    const int m0 = blockIdx.y * 64, n0 = blockIdx.x * 64;
    const int srow = tid >> 2, sco = (tid & 3) * 8;
    const short* ap = Qh + (size_t)(m0 + srow) * K + sco;
    const short* bp = Kh + (size_t)(n0 + srow) * K + sco;

    f4 acc[2][2] = {};
    for (int k0 = 0; k0 < K; k0 += 32) {
        s8v a8 = *(const s8v*)(ap + k0);
        s8v b8 = *(const s8v*)(bp + k0);
        __syncthreads();
        *(s8v*)&As[srow][sco] = a8;
        *(s8v*)&Bs[srow][sco] = b8;
        __syncthreads();
        s8v af[2], bf[2];
#pragma unroll
        for (int t = 0; t < 2; ++t) {
            af[t] = *(s8v*)&As[wm * 32 + t * 16 + l16][quad * 8];
            bf[t] = *(s8v*)&Bs[wn * 32 + t * 16 + l16][quad * 8];
        }
#pragma unroll
        for (int mt = 0; mt < 2; ++mt)
#pragma unroll
            for (int nt = 0; nt < 2; ++nt)
                acc[mt][nt] = __builtin_amdgcn_mfma_f32_16x16x32_bf16(
                    af[mt], bf[nt], acc[mt][nt], 0, 0, 0);
    }
#pragma unroll
    for (int mt = 0; mt < 2; ++mt)
#pragma unroll
        for (int nt = 0; nt < 2; ++nt)
#pragma unroll
            for (int r = 0; r < 4; ++r) {
                int row = m0 + wm * 32 + mt * 16 + quad * 4 + r;
                int col = n0 + wn * 32 + nt * 16 + l16;
                C[(size_t)row * N + col] = acc[mt][nt][r];
            }
}

// ------- fp64 L2 normalize + bf16 copy; y selects Q or K (R11-proven) -------
__global__ __launch_bounds__(256) void l2norm_f64bf16(
    double* __restrict__ dq, double* __restrict__ dk,
    short* __restrict__ hq, short* __restrict__ hk)
{
    double* d = blockIdx.y ? dk : dq;
    short*  h = blockIdx.y ? hk : hq;
    const int row = blockIdx.x;
    const int tid = threadIdx.x;
    double* p = d + (size_t)row * 1024 + tid * 4;
    double v0 = p[0], v1 = p[1], v2 = p[2], v3 = p[3];
    double s = v0 * v0 + v1 * v1 + v2 * v2 + v3 * v3;
#pragma unroll
    for (int off = 32; off > 0; off >>= 1) s += __shfl_down(s, off);
    __shared__ double ws[5];
    if ((tid & 63) == 0) ws[tid >> 6] = s;
    __syncthreads();
    if (tid == 0) ws[4] = fmax(sqrt(ws[0] + ws[1] + ws[2] + ws[3]), 1e-12);
    __syncthreads();
    double n = ws[4];
    double o0 = v0 / n, o1 = v1 / n, o2 = v2 / n, o3 = v3 / n;
    p[0] = o0; p[1] = o1; p[2] = o2; p[3] = o3;
    __align__(8) short hv[4] = {f2bf((float)o0), f2bf((float)o1),
                                f2bf((float)o2), f2bf((float)o3)};
    *(short4*)&h[(size_t)row * 1024 + tid * 4] = *(short4*)hv;
}

// ------- top-16 selection (register tournament, barrier-free per wave) +
//         fp64 rerank (one wave per candidate) + route -------
// Selection semantics identical to the serial tournament: order by
// (value desc, index asc). Global top-16 is contained in the union of the
// 4 per-wave top-16s, so per-wave tournaments + one 64->16 merge is exact.
__global__ __launch_bounds__(256) void topk_route(
    const float*  __restrict__ S,
    const double* __restrict__ Qd,
    const double* __restrict__ Kd,
    const float*  __restrict__ Vf,
    float* __restrict__ routes_out,
    float* __restrict__ weights_out,
    float* __restrict__ feat_out,
    int batch)
{
    const int P = 2048, D = 1024;
    __shared__ double qrow[1024];
    __shared__ float  cval[64];
    __shared__ int    cidx[64];
    __shared__ int    sel[16];
    __shared__ double cscore[16];
    __shared__ int    topi_s[8];
    __shared__ float  wts[8];

    const int p = blockIdx.x;
    const int tid = threadIdx.x;
    const int lane = tid & 63, wave = tid >> 6;

    // ---- load S row into registers (8 elems/thread), stage q row into LDS ----
    const float4* sr4 = (const float4*)(S + (size_t)p * P);
    const float4 s0 = sr4[tid];         // elements 4*tid .. 4*tid+3
    const float4 s1 = sr4[tid + 256];   // elements 1024+4*tid ..
    {
        const double* q = Qd + (size_t)p * D + tid * 4;
        qrow[tid * 4 + 0] = q[0]; qrow[tid * 4 + 1] = q[1];
        qrow[tid * 4 + 2] = q[2]; qrow[tid * 4 + 3] = q[3];
    }

    float v[8] = {s0.x, s0.y, s0.z, s0.w, s1.x, s1.y, s1.z, s1.w};
    int   ji[8];
#pragma unroll
    for (int e = 0; e < 8; ++e) {
        ji[e] = (e < 4) ? (4 * tid + e) : (1024 + 4 * tid + (e - 4));
        if (ji[e] == p) v[e] = -1e30f;   // diagonal mask
    }

    // per-lane local argmax (ji strictly increasing => '>' keeps lowest index on ties)
    float lv = v[0]; int li = ji[0];
#pragma unroll
    for (int e = 1; e < 8; ++e)
        if (v[e] > lv) { lv = v[e]; li = ji[e]; }

    // ---- per-wave top-16 register tournament (no barriers) ----
    float cv_ = -INFINITY; int ci_ = 0;
#pragma unroll 1
    for (int it = 0; it < 16; ++it) {
        float bv = lv; int bi = li;
#pragma unroll
        for (int off = 32; off > 0; off >>= 1) {
            float ov = __shfl_xor(bv, off);
            int   oi = __shfl_xor(bi, off);
            if (ov > bv || (ov == bv && oi < bi)) { bv = ov; bi = oi; }
        }
        if (lane == it) { cv_ = bv; ci_ = bi; }
        // invalidate winner and recompute local argmax (uniform, unrolled)
#pragma unroll
        for (int e = 0; e < 8; ++e)
            if (ji[e] == bi) v[e] = -INFINITY;
        lv = v[0]; li = ji[0];
#pragma unroll
        for (int e = 1; e < 8; ++e)
            if (v[e] > lv) { lv = v[e]; li = ji[e]; }
    }
    if (lane < 16) { cval[wave * 16 + lane] = cv_; cidx[wave * 16 + lane] = ci_; }
    __syncthreads();

    // ---- merge 64 -> 16 on wave 0 (indices are globally unique) ----
    if (wave == 0) {
        float mv = cval[lane]; int mi = cidx[lane];
#pragma unroll 1
        for (int it = 0; it < 16; ++it) {
            float bv = mv; int bi = mi;
#pragma unroll
            for (int off = 32; off > 0; off >>= 1) {
                float ov = __shfl_xor(bv, off);
                int   oi = __shfl_xor(bi, off);
                if (ov > bv || (ov == bv && oi < bi)) { bv = ov; bi = oi; }
            }
            if (lane == 0) sel[it] = bi;
            if (mi == bi) mv = -INFINITY;
        }
    }
    __syncthreads();

    // ---- fp64 rerank: one wave per candidate, 4 rounds; coalesced Kd reads ----
#pragma unroll 1
    for (int rr = 0; rr < 4; ++rr) {
        const int c = wave + rr * 4;
        const double* krow = Kd + (size_t)sel[c] * D;
        double s = 0.0;
#pragma unroll
        for (int j = 0; j < 16; ++j)
            s = fma(qrow[lane + j * 64], krow[lane + j * 64], s);
#pragma unroll
        for (int off = 32; off > 0; off >>= 1) s += __shfl_xor(s, off);
        if (lane == 0) cscore[c] = s;
    }
    __syncthreads();

    // ---- exact top-8 of 16 by fp64 score + softmax (serial, small) ----
    if (tid == 0) {
        unsigned used = 0;
        double tv[8]; int ti[8];
        for (int k = 0; k < 8; ++k) {
            int best = -1;
            for (int c = 0; c < 16; ++c) {
                if (used & (1u << c)) continue;
                if (best < 0 || cscore[c] > cscore[best] ||
                    (cscore[c] == cscore[best] && sel[c] < sel[best])) best = c;
            }
            used |= 1u << best;
            tv[k] = cscore[best]; ti[k] = sel[best];
        }
        double m = tv[0], e[8], sum = 0.0;
        for (int k = 0; k < 8; ++k) { e[k] = exp((tv[k] - m) / TEMP); sum += e[k]; }
        const size_t row = (size_t)batch * P + p;
        for (int k = 0; k < 8; ++k) {
            float wk = (float)(e[k] / sum);
            wts[k] = wk; topi_s[k] = ti[k];
            routes_out[row * 8 + k]  = (float)ti[k];
            weights_out[row * 8 + k] = wk;
        }
    }
    __syncthreads();

    // ---- V gather + weighted sum ----
    float4 a = {0.f, 0.f, 0.f, 0.f};
#pragma unroll
    for (int k = 0; k < 8; ++k) {
        const float4 v4 = ((const float4*)(Vf + (size_t)topi_s[k] * D))[tid];
        float wk = wts[k];
        a.x = fmaf(wk, v4.x, a.x);
        a.y = fmaf(wk, v4.y, a.y);
        a.z = fmaf(wk, v4.z, a.z);
        a.w = fmaf(wk, v4.w, a.w);
    }
    ((float4*)(feat_out + ((size_t)batch * P + p) * D))[tid] = a;
}

extern "C" void kernel_launch(void* const* d_in, const int* in_sizes, int n_in,
                              void* d_out, int out_size, void* d_ws, size_t ws_size,
                              hipStream_t stream)
{
    const float* x  = (const float*)d_in[0];  // (4,2049,1024)
    const float* Wq = (const float*)d_in[1];
    const float* bq = (const float*)d_in[2];
    const float* Wk = (const float*)d_in[3];
    const float* bk = (const float*)d_in[4];
    const float* Wv = (const float*)d_in[5];
    const float* bv = (const float*)d_in[6];

    const int B = 4, P = 2048, D = 1024;
    const size_t PD = (size_t)P * D;
    const size_t DD = (size_t)D * D;

    double* Qd   = (double*)d_ws;             // P*D f64
    double* Kd   = Qd + PD;
    double* xsc  = Kd + PD;                   // 2048
    double* wqsc = xsc + 2048;                // 1024
    double* wksc = wqsc + 1024;               // 1024
    short*  Qh   = (short*)(wksc + 1024);     // P*D bf16
    short*  Kh   = Qh + PD;
    short*  xh   = Kh + PD;                   // x bf16 hi
    short*  xlo  = xh + PD;                   // x bf16 lo
    short*  Wvh  = xlo + PD;                  // Wv bf16 hi
    short*  Wvl  = Wvh + DD;                  // Wv bf16 lo
    float*  Vf   = (float*)(Wvl + DD);        // P*D f32
    float*  Sf   = Vf + PD;                   // P*P f32
    signed char* Xl  = (signed char*)(Sf + (size_t)P * P);  // 4*P*D
    signed char* Wql = Xl + 4 * PD;                          // 4*D*D
    signed char* Wkl = Wql + 4 * DD;

    float* out     = (float*)d_out;
    float* routes  = out;
    float* weights = out + (size_t)B * P * 8;
    float* feat    = out + (size_t)B * P * 16;

    dim3 blk(256);
    quantize_rows<<<dim3(1024), blk, 0, stream>>>(Wq, Wql, (long)DD, wqsc);
    quantize_rows<<<dim3(1024), blk, 0, stream>>>(Wk, Wkl, (long)DD, wksc);
    tobf16_split<<<dim3(1024), blk, 0, stream>>>(Wv, Wvh, Wvl);

    for (int b = 0; b < B; ++b) {
        const float* xb = x + ((size_t)b * 2049 + 1) * D;  // rows 1..2048 contiguous
        quantize_rows<<<dim3(P), blk, 0, stream>>>(xb, Xl, (long)PD, xsc);
        tobf16_split<<<dim3(P), blk, 0, stream>>>(xb, xh, xlo);
        gemm_i8qk<<<dim3(16, 32, 2), blk, 0, stream>>>(Xl, Wql, Wkl, xsc, wqsc, wksc,
                                                       bq, bk, Qd, Kd);
        gemm_v64<<<dim3(16, 32), blk, 0, stream>>>(xh, xlo, Wvh, Wvl, bv, Vf);
        l2norm_f64bf16<<<dim3(P, 2), blk, 0, stream>>>(Qd, Kd, Qh, Kh);
        gemm_score<<<dim3(32, 32), blk, 0, stream>>>(Qh, Kh, Sf);
        topk_route<<<dim3(P), blk, 0, stream>>>(Sf, Qd, Kd, Vf, routes, weights, feat, b);
    }
}

// Round 3
// 875.527 us; speedup vs baseline: 1.0836x; 1.0836x over previous
//
#include <hip/hip_runtime.h>
#include <hip/hip_bf16.h>
#include <math.h>

#define TEMP 0.1
#define NC 12   // rerank candidate count (true top-8 ⊂ bf16 top-12: >50-sigma margin)

typedef float f4 __attribute__((ext_vector_type(4)));
typedef short s8v __attribute__((ext_vector_type(8)));
typedef int   i4v __attribute__((ext_vector_type(4)));

__device__ inline short f2bf(float f) {
    __hip_bfloat16 h = __float2bfloat16(f);
    return *reinterpret_cast<short*>(&h);
}
__device__ inline float bf2f(short s) {
    __hip_bfloat16 h = *reinterpret_cast<__hip_bfloat16*>(&s);
    return __bfloat162float(h);
}

// ---------- quantize rows of 1024 to 4 balanced int8 limbs (R6 code; numerics re-tested) ----------
__global__ __launch_bounds__(256) void quantize_rows(
    const float* __restrict__ src, signed char* __restrict__ limbs,
    long plane_stride, double* __restrict__ scale)
{
    const int row = blockIdx.x, tid = threadIdx.x;
    const float4 v = ((const float4*)(src + (size_t)row * 1024))[tid];
    float m = fmaxf(fmaxf(fabsf(v.x), fabsf(v.y)), fmaxf(fabsf(v.z), fabsf(v.w)));
#pragma unroll
    for (int off = 32; off > 0; off >>= 1) m = fmaxf(m, __shfl_down(m, off));
    __shared__ float wmax[4];
    __shared__ int ssig;
    if ((tid & 63) == 0) wmax[tid >> 6] = m;
    __syncthreads();
    if (tid == 0) {
        float rm = fmaxf(fmaxf(wmax[0], wmax[1]), fmaxf(wmax[2], wmax[3]));
        int sig = (rm > 0.f) ? (29 - ilogbf(rm)) : 0;
        ssig = sig;
        scale[row] = ldexp(1.0, -sig);
    }
    __syncthreads();
    const double s2 = ldexp(1.0, ssig);
    float xs[4] = {v.x, v.y, v.z, v.w};
    signed char out[4][4];
#pragma unroll
    for (int e = 0; e < 4; ++e) {
        long X = __double2ll_rn((double)xs[e] * s2);
#pragma unroll
        for (int l = 0; l < 3; ++l) {
            int d = (int)(((X + 128) & 255) - 128);
            out[l][e] = (signed char)d;
            X = (X - d) >> 8;
        }
        out[3][e] = (signed char)X;
    }
#pragma unroll
    for (int l = 0; l < 4; ++l)
        *(char4*)&limbs[(size_t)l * plane_stride + (size_t)row * 1024 + tid * 4] =
            *(char4*)&out[l][0];
}

// ---------- fp32 -> bf16 hi/lo split planes ----------
__global__ __launch_bounds__(256) void tobf16_split(
    const float* __restrict__ src, short* __restrict__ hi, short* __restrict__ lo)
{
    const int row = blockIdx.x, tid = threadIdx.x;
    const float4 v = ((const float4*)(src + (size_t)row * 1024))[tid];
    float xs[4] = {v.x, v.y, v.z, v.w};
    __align__(8) short h[4], l[4];
#pragma unroll
    for (int e = 0; e < 4; ++e) {
        h[e] = f2bf(xs[e]);
        l[e] = f2bf(xs[e] - bf2f(h[e]));
    }
    *(short4*)&hi[(size_t)row * 1024 + tid * 4] = *(short4*)h;
    *(short4*)&lo[(size_t)row * 1024 + tid * 4] = *(short4*)l;
}

// ---------- exact i8-MFMA projection: 4 limb planes, 13 pairs (i+j>=2), 5 levels ----------
__global__ __launch_bounds__(256) void gemm_i8qk(
    const signed char* __restrict__ Xl,
    const signed char* __restrict__ Wql,
    const signed char* __restrict__ Wkl,
    const double* __restrict__ xsc,
    const double* __restrict__ wqsc, const double* __restrict__ wksc,
    const float* __restrict__ bq, const float* __restrict__ bk,
    double* __restrict__ Qd, double* __restrict__ Kd)
{
    const int K = 1024, N = 1024;
    const long MK = 2048L * 1024, NK = 1024L * 1024;
    const signed char* Wl = blockIdx.z ? Wkl : Wql;
    const double* wsc = blockIdx.z ? wksc : wqsc;
    const float* bias = blockIdx.z ? bk : bq;
    double* C = blockIdx.z ? Kd : Qd;

    __shared__ __align__(16) signed char Asm[4][64][80];
    __shared__ __align__(16) signed char Bsm[4][64][80];

    const int tid  = threadIdx.x;
    const int lane = tid & 63, wave = tid >> 6;
    const int wm = wave >> 1, wn = wave & 1;
    const int quad = lane >> 4, l16 = lane & 15;
    const int m0 = blockIdx.y * 64, n0 = blockIdx.x * 64;

    const int srow = tid >> 2, skq = (tid & 3) * 16;
    const signed char* ap = Xl + (size_t)(m0 + srow) * K + skq;
    const signed char* bp = Wl + (size_t)(n0 + srow) * K + skq;

    i4v acc[5][2][2] = {};   // level s = i+j-2

    i4v at[4], bt[4];
#pragma unroll
    for (int l = 0; l < 4; ++l) {
        at[l] = *(const i4v*)(ap + l * MK);
        bt[l] = *(const i4v*)(bp + l * NK);
    }

    for (int k0 = 0; k0 < K; k0 += 64) {
        __syncthreads();
#pragma unroll
        for (int l = 0; l < 4; ++l) {
            *(i4v*)&Asm[l][srow][skq] = at[l];
            *(i4v*)&Bsm[l][srow][skq] = bt[l];
        }
        __syncthreads();

        if (k0 + 64 < K) {
#pragma unroll
            for (int l = 0; l < 4; ++l) {
                at[l] = *(const i4v*)(ap + l * MK + k0 + 64);
                bt[l] = *(const i4v*)(bp + l * NK + k0 + 64);
            }
        }

        i4v bF[4][2];
#pragma unroll
        for (int j = 0; j < 4; ++j)
#pragma unroll
            for (int nt = 0; nt < 2; ++nt)
                bF[j][nt] = *(const i4v*)&Bsm[j][wn * 32 + nt * 16 + l16][quad * 16];

#pragma unroll
        for (int i = 0; i < 4; ++i) {
            i4v a0 = *(const i4v*)&Asm[i][wm * 32 +      l16][quad * 16];
            i4v a1 = *(const i4v*)&Asm[i][wm * 32 + 16 + l16][quad * 16];
#pragma unroll
            for (int j = 0; j < 4; ++j) {
                if (i + j < 2) continue;
                const int s = i + j - 2;
                acc[s][0][0] = __builtin_amdgcn_mfma_i32_16x16x64_i8(a0, bF[j][0], acc[s][0][0], 0, 0, 0);
                acc[s][0][1] = __builtin_amdgcn_mfma_i32_16x16x64_i8(a0, bF[j][1], acc[s][0][1], 0, 0, 0);
                acc[s][1][0] = __builtin_amdgcn_mfma_i32_16x16x64_i8(a1, bF[j][0], acc[s][1][0], 0, 0, 0);
                acc[s][1][1] = __builtin_amdgcn_mfma_i32_16x16x64_i8(a1, bF[j][1], acc[s][1][1], 0, 0, 0);
            }
        }
    }

    const double wt0 = ldexp(1.0, 16), wt1 = ldexp(1.0, 24), wt2 = ldexp(1.0, 32);
    const double wt3 = ldexp(1.0, 40), wt4 = ldexp(1.0, 48);
#pragma unroll
    for (int mt = 0; mt < 2; ++mt)
#pragma unroll
        for (int nt = 0; nt < 2; ++nt)
#pragma unroll
            for (int r = 0; r < 4; ++r) {
                int row = m0 + wm * 32 + mt * 16 + quad * 4 + r;
                int col = n0 + wn * 32 + nt * 16 + l16;
                double dsum = wt0 * (double)acc[0][mt][nt][r]
                            + wt1 * (double)acc[1][mt][nt][r]
                            + wt2 * (double)acc[2][mt][nt][r]
                            + wt3 * (double)acc[3][mt][nt][r]
                            + wt4 * (double)acc[4][mt][nt][r];
                C[(size_t)row * N + col] = dsum * xsc[row] * wsc[col] + (double)bias[col];
            }
}

// ------- V projection from precomputed bf16 hi/lo planes -------
__global__ __launch_bounds__(256) void gemm_v64(
    const short* __restrict__ Ahp, const short* __restrict__ Alp,
    const short* __restrict__ Bhp, const short* __restrict__ Blp,
    const float* __restrict__ bias, float* __restrict__ C)
{
    const int K = 1024, N = 1024;
    __shared__ short Ah[64][40];
    __shared__ short Al[64][40];
    __shared__ short Bh[64][40];
    __shared__ short Bl[64][40];

    const int tid = threadIdx.x, lane = tid & 63, wave = tid >> 6;
    const int wm = wave >> 1, wn = wave & 1;
    const int quad = lane >> 4, l16 = lane & 15;
    const int m0 = blockIdx.y * 64, n0 = blockIdx.x * 64;
    const int srow = tid >> 2, sco = (tid & 3) * 8;
    const size_t aoff = (size_t)(m0 + srow) * K + sco;
    const size_t boff = (size_t)(n0 + srow) * K + sco;

    f4 acc[2][2] = {};
    for (int k0 = 0; k0 < K; k0 += 32) {
        s8v ah = *(const s8v*)(Ahp + aoff + k0);
        s8v al = *(const s8v*)(Alp + aoff + k0);
        s8v bh = *(const s8v*)(Bhp + boff + k0);
        s8v bl = *(const s8v*)(Blp + boff + k0);
        __syncthreads();
        *(s8v*)&Ah[srow][sco] = ah;
        *(s8v*)&Al[srow][sco] = al;
        *(s8v*)&Bh[srow][sco] = bh;
        *(s8v*)&Bl[srow][sco] = bl;
        __syncthreads();

        s8v af[2], afl[2], bf[2], bfl[2];
#pragma unroll
        for (int t = 0; t < 2; ++t) {
            af[t]  = *(s8v*)&Ah[wm * 32 + t * 16 + l16][quad * 8];
            afl[t] = *(s8v*)&Al[wm * 32 + t * 16 + l16][quad * 8];
            bf[t]  = *(s8v*)&Bh[wn * 32 + t * 16 + l16][quad * 8];
            bfl[t] = *(s8v*)&Bl[wn * 32 + t * 16 + l16][quad * 8];
        }
#pragma unroll
        for (int mt = 0; mt < 2; ++mt)
#pragma unroll
            for (int nt = 0; nt < 2; ++nt) {
                acc[mt][nt] = __builtin_amdgcn_mfma_f32_16x16x32_bf16(af[mt],  bf[nt],  acc[mt][nt], 0, 0, 0);
                acc[mt][nt] = __builtin_amdgcn_mfma_f32_16x16x32_bf16(af[mt],  bfl[nt], acc[mt][nt], 0, 0, 0);
                acc[mt][nt] = __builtin_amdgcn_mfma_f32_16x16x32_bf16(afl[mt], bf[nt],  acc[mt][nt], 0, 0, 0);
            }
    }
#pragma unroll
    for (int mt = 0; mt < 2; ++mt)
#pragma unroll
        for (int nt = 0; nt < 2; ++nt)
#pragma unroll
            for (int r = 0; r < 4; ++r) {
                int row = m0 + wm * 32 + mt * 16 + quad * 4 + r;
                int col = n0 + wn * 32 + nt * 16 + l16;
                C[(size_t)row * N + col] = acc[mt][nt][r] + bias[col];
            }
}

// ------- score GEMM: 64x64 tile, bf16 inputs, fp32 out -------
__global__ __launch_bounds__(256) void gemm_score(
    const short* __restrict__ Qh, const short* __restrict__ Kh,
    float* __restrict__ C)
{
    const int K = 1024, N = 2048;
    __shared__ short As[64][40];
    __shared__ short Bs[64][40];
    const int tid = threadIdx.x, lane = tid & 63, wave = tid >> 6;
    const int wm = wave >> 1, wn = wave & 1;
    const int quad = lane >> 4, l16 = lane & 15;
    const int m0 = blockIdx.y * 64, n0 = blockIdx.x * 64;
    const int srow = tid >> 2, sco = (tid & 3) * 8;
    const short* ap = Qh + (size_t)(m0 + srow) * K + sco;
    const short* bp = Kh + (size_t)(n0 + srow) * K + sco;

    f4 acc[2][2] = {};
    for (int k0 = 0; k0 < K; k0 += 32) {
        s8v a8 = *(const s8v*)(ap + k0);
        s8v b8 = *(const s8v*)(bp + k0);
        __syncthreads();
        *(s8v*)&As[srow][sco] = a8;
        *(s8v*)&Bs[srow][sco] = b8;
        __syncthreads();
        s8v af[2], bf[2];
#pragma unroll
        for (int t = 0; t < 2; ++t) {
            af[t] = *(s8v*)&As[wm * 32 + t * 16 + l16][quad * 8];
            bf[t] = *(s8v*)&Bs[wn * 32 + t * 16 + l16][quad * 8];
        }
#pragma unroll
        for (int mt = 0; mt < 2; ++mt)
#pragma unroll
            for (int nt = 0; nt < 2; ++nt)
                acc[mt][nt] = __builtin_amdgcn_mfma_f32_16x16x32_bf16(
                    af[mt], bf[nt], acc[mt][nt], 0, 0, 0);
    }
#pragma unroll
    for (int mt = 0; mt < 2; ++mt)
#pragma unroll
        for (int nt = 0; nt < 2; ++nt)
#pragma unroll
            for (int r = 0; r < 4; ++r) {
                int row = m0 + wm * 32 + mt * 16 + quad * 4 + r;
                int col = n0 + wn * 32 + nt * 16 + l16;
                C[(size_t)row * N + col] = acc[mt][nt][r];
            }
}

// ------- fp64 L2 normalize + bf16 copy; y selects Q or K; K also written fp32 -------
__global__ __launch_bounds__(256) void l2norm_f64bf16(
    double* __restrict__ dq, double* __restrict__ dk,
    short* __restrict__ hq, short* __restrict__ hk,
    float* __restrict__ fk)
{
    double* d = blockIdx.y ? dk : dq;
    short*  h = blockIdx.y ? hk : hq;
    const int row = blockIdx.x;
    const int tid = threadIdx.x;
    double* p = d + (size_t)row * 1024 + tid * 4;
    double v0 = p[0], v1 = p[1], v2 = p[2], v3 = p[3];
    double s = v0 * v0 + v1 * v1 + v2 * v2 + v3 * v3;
#pragma unroll
    for (int off = 32; off > 0; off >>= 1) s += __shfl_down(s, off);
    __shared__ double ws[5];
    if ((tid & 63) == 0) ws[tid >> 6] = s;
    __syncthreads();
    if (tid == 0) ws[4] = fmax(sqrt(ws[0] + ws[1] + ws[2] + ws[3]), 1e-12);
    __syncthreads();
    double n = ws[4];
    double o0 = v0 / n, o1 = v1 / n, o2 = v2 / n, o3 = v3 / n;
    p[0] = o0; p[1] = o1; p[2] = o2; p[3] = o3;
    __align__(8) short hv[4] = {f2bf((float)o0), f2bf((float)o1),
                                f2bf((float)o2), f2bf((float)o3)};
    *(short4*)&h[(size_t)row * 1024 + tid * 4] = *(short4*)hv;
    if (blockIdx.y) {
        float4 fv = make_float4((float)o0, (float)o1, (float)o2, (float)o3);
        ((float4*)&fk[(size_t)row * 1024])[tid] = fv;
    }
}

// ------- top-NC selection (register tournament) + rerank from fp32 K
//         (fp64 accumulate) + V-row prefetch + route -------
__global__ __launch_bounds__(256) void topk_route(
    const float*  __restrict__ S,
    const double* __restrict__ Qd,
    const float*  __restrict__ Kf,
    const float*  __restrict__ Vf,
    float* __restrict__ routes_out,
    float* __restrict__ weights_out,
    float* __restrict__ feat_out,
    int batch)
{
    const int P = 2048, D = 1024;
    __shared__ double qrow[1024];
    __shared__ float  cval[4 * NC];
    __shared__ int    cidx[4 * NC];
    __shared__ int    sel[NC];
    __shared__ double cscore[NC];
    __shared__ int    topi_s[8];
    __shared__ float  wts[8];

    const int p = blockIdx.x;
    const int tid = threadIdx.x;
    const int lane = tid & 63, wave = tid >> 6;

    // ---- load S row into registers (8 elems/thread), stage q row into LDS ----
    const float4* sr4 = (const float4*)(S + (size_t)p * P);
    const float4 s0 = sr4[tid];
    const float4 s1 = sr4[tid + 256];
    {
        const double* q = Qd + (size_t)p * D + tid * 4;
        qrow[tid * 4 + 0] = q[0]; qrow[tid * 4 + 1] = q[1];
        qrow[tid * 4 + 2] = q[2]; qrow[tid * 4 + 3] = q[3];
    }

    float v[8] = {s0.x, s0.y, s0.z, s0.w, s1.x, s1.y, s1.z, s1.w};
    int   ji[8];
#pragma unroll
    for (int e = 0; e < 8; ++e) {
        ji[e] = (e < 4) ? (4 * tid + e) : (1024 + 4 * tid + (e - 4));
        if (ji[e] == p) v[e] = -1e30f;   // diagonal mask
    }

    float lv = v[0]; int li = ji[0];
#pragma unroll
    for (int e = 1; e < 8; ++e)
        if (v[e] > lv) { lv = v[e]; li = ji[e]; }

    // ---- per-wave top-NC register tournament (no barriers) ----
    float cv_ = -INFINITY; int ci_ = 0x7fffffff;
#pragma unroll 1
    for (int it = 0; it < NC; ++it) {
        float bv = lv; int bi = li;
#pragma unroll
        for (int off = 32; off > 0; off >>= 1) {
            float ov = __shfl_xor(bv, off);
            int   oi = __shfl_xor(bi, off);
            if (ov > bv || (ov == bv && oi < bi)) { bv = ov; bi = oi; }
        }
        if (lane == it) { cv_ = bv; ci_ = bi; }
#pragma unroll
        for (int e = 0; e < 8; ++e)
            if (ji[e] == bi) v[e] = -INFINITY;
        lv = v[0]; li = ji[0];
#pragma unroll
        for (int e = 1; e < 8; ++e)
            if (v[e] > lv) { lv = v[e]; li = ji[e]; }
    }
    if (lane < NC) { cval[wave * NC + lane] = cv_; cidx[wave * NC + lane] = ci_; }
    __syncthreads();

    // ---- merge 4*NC -> NC on wave 0 (indices globally unique) ----
    if (wave == 0) {
        float mv = (lane < 4 * NC) ? cval[lane] : -INFINITY;
        int   mi = (lane < 4 * NC) ? cidx[lane] : 0x7fffffff;
#pragma unroll 1
        for (int it = 0; it < NC; ++it) {
            float bv = mv; int bi = mi;
#pragma unroll
            for (int off = 32; off > 0; off >>= 1) {
                float ov = __shfl_xor(bv, off);
                int   oi = __shfl_xor(bi, off);
                if (ov > bv || (ov == bv && oi < bi)) { bv = ov; bi = oi; }
            }
            if (lane == 0) sel[it] = bi;
            if (mi == bi) mv = -INFINITY;
        }
    }
    __syncthreads();

    // ---- prefetch all NC candidate V rows (every 64B line touched);
    //      consumed after rerank so loads stay in flight under it ----
    float pfv[NC];
#pragma unroll
    for (int c = 0; c < NC; ++c)
        pfv[c] = Vf[(size_t)sel[c] * D + tid * 4];

    // ---- fp64-accumulate rerank from fp32 K rows: one wave per candidate ----
#pragma unroll 1
    for (int rr = 0; rr < NC / 4; ++rr) {
        const int c = wave + rr * 4;
        const float* krow = Kf + (size_t)sel[c] * D;
        double sa = 0.0, sb = 0.0;
#pragma unroll
        for (int j = 0; j < 8; ++j) {
            const float2 kk = *(const float2*)&krow[lane * 2 + j * 128];
            sa = fma(qrow[lane * 2 + 0 + j * 128], (double)kk.x, sa);
            sb = fma(qrow[lane * 2 + 1 + j * 128], (double)kk.y, sb);
        }
        double s = sa + sb;
#pragma unroll
        for (int off = 32; off > 0; off >>= 1) s += __shfl_xor(s, off);
        if (lane == 0) cscore[c] = s;
    }

    // consume prefetch values (wait lands here; keeps loads live, no output effect)
    {
        float pf = 0.f;
#pragma unroll
        for (int c = 0; c < NC; ++c) pf += pfv[c];
        asm volatile("" :: "v"(pf));
    }
    __syncthreads();

    // ---- exact top-8 of NC by fp64 score + softmax (serial, small) ----
    if (tid == 0) {
        unsigned used = 0;
        double tv[8]; int ti[8];
        for (int k = 0; k < 8; ++k) {
            int best = -1;
            for (int c = 0; c < NC; ++c) {
                if (used & (1u << c)) continue;
                if (best < 0 || cscore[c] > cscore[best] ||
                    (cscore[c] == cscore[best] && sel[c] < sel[best])) best = c;
            }
            used |= 1u << best;
            tv[k] = cscore[best]; ti[k] = sel[best];
        }
        double m = tv[0], e[8], sum = 0.0;
        for (int k = 0; k < 8; ++k) { e[k] = exp((tv[k] - m) / TEMP); sum += e[k]; }
        const size_t row = (size_t)batch * P + p;
        for (int k = 0; k < 8; ++k) {
            float wk = (float)(e[k] / sum);
            wts[k] = wk; topi_s[k] = ti[k];
            routes_out[row * 8 + k]  = (float)ti[k];
            weights_out[row * 8 + k] = wk;
        }
    }
    __syncthreads();

    // ---- V gather + weighted sum (rows L2-hot from prefetch) ----
    float4 a = {0.f, 0.f, 0.f, 0.f};
#pragma unroll
    for (int k = 0; k < 8; ++k) {
        const float4 v4 = ((const float4*)(Vf + (size_t)topi_s[k] * D))[tid];
        float wk = wts[k];
        a.x = fmaf(wk, v4.x, a.x);
        a.y = fmaf(wk, v4.y, a.y);
        a.z = fmaf(wk, v4.z, a.z);
        a.w = fmaf(wk, v4.w, a.w);
    }
    ((float4*)(feat_out + ((size_t)batch * P + p) * D))[tid] = a;
}

extern "C" void kernel_launch(void* const* d_in, const int* in_sizes, int n_in,
                              void* d_out, int out_size, void* d_ws, size_t ws_size,
                              hipStream_t stream)
{
    const float* x  = (const float*)d_in[0];  // (4,2049,1024)
    const float* Wq = (const float*)d_in[1];
    const float* bq = (const float*)d_in[2];
    const float* Wk = (const float*)d_in[3];
    const float* bk = (const float*)d_in[4];
    const float* Wv = (const float*)d_in[5];
    const float* bv = (const float*)d_in[6];

    const int B = 4, P = 2048, D = 1024;
    const size_t PD = (size_t)P * D;
    const size_t DD = (size_t)D * D;

    double* Qd   = (double*)d_ws;             // P*D f64
    double* Kd   = Qd + PD;
    double* xsc  = Kd + PD;                   // 2048
    double* wqsc = xsc + 2048;                // 1024
    double* wksc = wqsc + 1024;               // 1024
    short*  Qh   = (short*)(wksc + 1024);     // P*D bf16
    short*  Kh   = Qh + PD;
    short*  xh   = Kh + PD;                   // x bf16 hi (dead after gemm_v64)
    short*  xlo  = xh + PD;                   // x bf16 lo (dead after gemm_v64)
    short*  Wvh  = xlo + PD;                  // Wv bf16 hi
    short*  Wvl  = Wvh + DD;                  // Wv bf16 lo
    float*  Vf   = (float*)(Wvl + DD);        // P*D f32
    float*  Sf   = Vf + PD;                   // P*P f32
    signed char* Xl  = (signed char*)(Sf + (size_t)P * P);  // 4*P*D
    signed char* Wql = Xl + 4 * PD;                          // 4*D*D
    signed char* Wkl = Wql + 4 * DD;

    // fp32 normalized K for rerank: reuse xh+xlo region (exactly P*D floats)
    float* Kf = (float*)xh;

    float* out     = (float*)d_out;
    float* routes  = out;
    float* weights = out + (size_t)B * P * 8;
    float* feat    = out + (size_t)B * P * 16;

    dim3 blk(256);
    quantize_rows<<<dim3(1024), blk, 0, stream>>>(Wq, Wql, (long)DD, wqsc);
    quantize_rows<<<dim3(1024), blk, 0, stream>>>(Wk, Wkl, (long)DD, wksc);
    tobf16_split<<<dim3(1024), blk, 0, stream>>>(Wv, Wvh, Wvl);

    for (int b = 0; b < B; ++b) {
        const float* xb = x + ((size_t)b * 2049 + 1) * D;  // rows 1..2048 contiguous
        quantize_rows<<<dim3(P), blk, 0, stream>>>(xb, Xl, (long)PD, xsc);
        tobf16_split<<<dim3(P), blk, 0, stream>>>(xb, xh, xlo);
        gemm_i8qk<<<dim3(16, 32, 2), blk, 0, stream>>>(Xl, Wql, Wkl, xsc, wqsc, wksc,
                                                       bq, bk, Qd, Kd);
        gemm_v64<<<dim3(16, 32), blk, 0, stream>>>(xh, xlo, Wvh, Wvl, bv, Vf);
        // l2norm overwrites xh/xlo region with Kf (fp32 normalized K) — v64 done reading
        l2norm_f64bf16<<<dim3(P, 2), blk, 0, stream>>>(Qd, Kd, Qh, Kh, Kf);
        gemm_score<<<dim3(32, 32), blk, 0, stream>>>(Qh, Kh, Sf);
        topk_route<<<dim3(P), blk, 0, stream>>>(Sf, Qd, Kf, Vf, routes, weights, feat, b);
    }
}

// Round 4
// 775.935 us; speedup vs baseline: 1.2227x; 1.1284x over previous
//
#include <hip/hip_runtime.h>
#include <hip/hip_bf16.h>
#include <math.h>

#define TEMP 0.1
#define NC 12   // rerank candidate count (true top-8 ⊂ bf16 top-12: >50-sigma margin)

typedef float f4 __attribute__((ext_vector_type(4)));
typedef short s8v __attribute__((ext_vector_type(8)));
typedef int   i4v __attribute__((ext_vector_type(4)));

__device__ inline short f2bf(float f) {
    __hip_bfloat16 h = __float2bfloat16(f);
    return *reinterpret_cast<short*>(&h);
}
__device__ inline float bf2f(short s) {
    __hip_bfloat16 h = *reinterpret_cast<__hip_bfloat16*>(&s);
    return __bfloat162float(h);
}

// ---------- quantize rows of 1024 to 4 balanced int8 limbs (W setup only) ----------
__global__ __launch_bounds__(256) void quantize_rows(
    const float* __restrict__ src, signed char* __restrict__ limbs,
    long plane_stride, double* __restrict__ scale)
{
    const int row = blockIdx.x, tid = threadIdx.x;
    const float4 v = ((const float4*)(src + (size_t)row * 1024))[tid];
    float m = fmaxf(fmaxf(fabsf(v.x), fabsf(v.y)), fmaxf(fabsf(v.z), fabsf(v.w)));
#pragma unroll
    for (int off = 32; off > 0; off >>= 1) m = fmaxf(m, __shfl_down(m, off));
    __shared__ float wmax[4];
    __shared__ int ssig;
    if ((tid & 63) == 0) wmax[tid >> 6] = m;
    __syncthreads();
    if (tid == 0) {
        float rm = fmaxf(fmaxf(wmax[0], wmax[1]), fmaxf(wmax[2], wmax[3]));
        int sig = (rm > 0.f) ? (29 - ilogbf(rm)) : 0;
        ssig = sig;
        scale[row] = ldexp(1.0, -sig);
    }
    __syncthreads();
    const double s2 = ldexp(1.0, ssig);
    float xs[4] = {v.x, v.y, v.z, v.w};
    signed char out[4][4];
#pragma unroll
    for (int e = 0; e < 4; ++e) {
        long X = __double2ll_rn((double)xs[e] * s2);
#pragma unroll
        for (int l = 0; l < 3; ++l) {
            int d = (int)(((X + 128) & 255) - 128);
            out[l][e] = (signed char)d;
            X = (X - d) >> 8;
        }
        out[3][e] = (signed char)X;
    }
#pragma unroll
    for (int l = 0; l < 4; ++l)
        *(char4*)&limbs[(size_t)l * plane_stride + (size_t)row * 1024 + tid * 4] =
            *(char4*)&out[l][0];
}

// ---------- fp32 -> bf16 hi/lo split planes (Wv setup only) ----------
__global__ __launch_bounds__(256) void tobf16_split(
    const float* __restrict__ src, short* __restrict__ hi, short* __restrict__ lo)
{
    const int row = blockIdx.x, tid = threadIdx.x;
    const float4 v = ((const float4*)(src + (size_t)row * 1024))[tid];
    float xs[4] = {v.x, v.y, v.z, v.w};
    __align__(8) short h[4], l[4];
#pragma unroll
    for (int e = 0; e < 4; ++e) {
        h[e] = f2bf(xs[e]);
        l[e] = f2bf(xs[e] - bf2f(h[e]));
    }
    *(short4*)&hi[(size_t)row * 1024 + tid * 4] = *(short4*)h;
    *(short4*)&lo[(size_t)row * 1024 + tid * 4] = *(short4*)l;
}

// ---------- fused x prep: int8 limb quantize + bf16 hi/lo split (single read of x) ----------
__global__ __launch_bounds__(256) void prep_x(
    const float* __restrict__ src, signed char* __restrict__ limbs,
    long plane_stride, double* __restrict__ scale,
    short* __restrict__ hi, short* __restrict__ lo)
{
    const int row = blockIdx.x, tid = threadIdx.x;
    const float4 v = ((const float4*)(src + (size_t)row * 1024))[tid];
    float m = fmaxf(fmaxf(fabsf(v.x), fabsf(v.y)), fmaxf(fabsf(v.z), fabsf(v.w)));
#pragma unroll
    for (int off = 32; off > 0; off >>= 1) m = fmaxf(m, __shfl_down(m, off));
    __shared__ float wmax[4];
    __shared__ int ssig;
    if ((tid & 63) == 0) wmax[tid >> 6] = m;
    __syncthreads();
    if (tid == 0) {
        float rm = fmaxf(fmaxf(wmax[0], wmax[1]), fmaxf(wmax[2], wmax[3]));
        int sig = (rm > 0.f) ? (29 - ilogbf(rm)) : 0;
        ssig = sig;
        scale[row] = ldexp(1.0, -sig);
    }
    __syncthreads();
    const double s2 = ldexp(1.0, ssig);
    float xs[4] = {v.x, v.y, v.z, v.w};
    signed char out[4][4];
    __align__(8) short h[4], l[4];
#pragma unroll
    for (int e = 0; e < 4; ++e) {
        long X = __double2ll_rn((double)xs[e] * s2);
#pragma unroll
        for (int lmb = 0; lmb < 3; ++lmb) {
            int d = (int)(((X + 128) & 255) - 128);
            out[lmb][e] = (signed char)d;
            X = (X - d) >> 8;
        }
        out[3][e] = (signed char)X;
        h[e] = f2bf(xs[e]);
        l[e] = f2bf(xs[e] - bf2f(h[e]));
    }
#pragma unroll
    for (int lmb = 0; lmb < 4; ++lmb)
        *(char4*)&limbs[(size_t)lmb * plane_stride + (size_t)row * 1024 + tid * 4] =
            *(char4*)&out[lmb][0];
    *(short4*)&hi[(size_t)row * 1024 + tid * 4] = *(short4*)h;
    *(short4*)&lo[(size_t)row * 1024 + tid * 4] = *(short4*)l;
}

// ---------- exact i8-MFMA projection -> fp32 output (limb recombination stays fp64) ----------
__global__ __launch_bounds__(256) void gemm_i8qk(
    const signed char* __restrict__ Xl,
    const signed char* __restrict__ Wql,
    const signed char* __restrict__ Wkl,
    const double* __restrict__ xsc,
    const double* __restrict__ wqsc, const double* __restrict__ wksc,
    const float* __restrict__ bq, const float* __restrict__ bk,
    float* __restrict__ Qf, float* __restrict__ Kf)
{
    const int K = 1024, N = 1024;
    const long MK = 2048L * 1024, NK = 1024L * 1024;
    const signed char* Wl = blockIdx.z ? Wkl : Wql;
    const double* wsc = blockIdx.z ? wksc : wqsc;
    const float* bias = blockIdx.z ? bk : bq;
    float* C = blockIdx.z ? Kf : Qf;

    __shared__ __align__(16) signed char Asm[4][64][80];
    __shared__ __align__(16) signed char Bsm[4][64][80];

    const int tid  = threadIdx.x;
    const int lane = tid & 63, wave = tid >> 6;
    const int wm = wave >> 1, wn = wave & 1;
    const int quad = lane >> 4, l16 = lane & 15;
    const int m0 = blockIdx.y * 64, n0 = blockIdx.x * 64;

    const int srow = tid >> 2, skq = (tid & 3) * 16;
    const signed char* ap = Xl + (size_t)(m0 + srow) * K + skq;
    const signed char* bp = Wl + (size_t)(n0 + srow) * K + skq;

    i4v acc[5][2][2] = {};   // level s = i+j-2

    i4v at[4], bt[4];
#pragma unroll
    for (int l = 0; l < 4; ++l) {
        at[l] = *(const i4v*)(ap + l * MK);
        bt[l] = *(const i4v*)(bp + l * NK);
    }

    for (int k0 = 0; k0 < K; k0 += 64) {
        __syncthreads();
#pragma unroll
        for (int l = 0; l < 4; ++l) {
            *(i4v*)&Asm[l][srow][skq] = at[l];
            *(i4v*)&Bsm[l][srow][skq] = bt[l];
        }
        __syncthreads();

        if (k0 + 64 < K) {
#pragma unroll
            for (int l = 0; l < 4; ++l) {
                at[l] = *(const i4v*)(ap + l * MK + k0 + 64);
                bt[l] = *(const i4v*)(bp + l * NK + k0 + 64);
            }
        }

        i4v bF[4][2];
#pragma unroll
        for (int j = 0; j < 4; ++j)
#pragma unroll
            for (int nt = 0; nt < 2; ++nt)
                bF[j][nt] = *(const i4v*)&Bsm[j][wn * 32 + nt * 16 + l16][quad * 16];

#pragma unroll
        for (int i = 0; i < 4; ++i) {
            i4v a0 = *(const i4v*)&Asm[i][wm * 32 +      l16][quad * 16];
            i4v a1 = *(const i4v*)&Asm[i][wm * 32 + 16 + l16][quad * 16];
#pragma unroll
            for (int j = 0; j < 4; ++j) {
                if (i + j < 2) continue;
                const int s = i + j - 2;
                acc[s][0][0] = __builtin_amdgcn_mfma_i32_16x16x64_i8(a0, bF[j][0], acc[s][0][0], 0, 0, 0);
                acc[s][0][1] = __builtin_amdgcn_mfma_i32_16x16x64_i8(a0, bF[j][1], acc[s][0][1], 0, 0, 0);
                acc[s][1][0] = __builtin_amdgcn_mfma_i32_16x16x64_i8(a1, bF[j][0], acc[s][1][0], 0, 0, 0);
                acc[s][1][1] = __builtin_amdgcn_mfma_i32_16x16x64_i8(a1, bF[j][1], acc[s][1][1], 0, 0, 0);
            }
        }
    }

    const double wt0 = ldexp(1.0, 16), wt1 = ldexp(1.0, 24), wt2 = ldexp(1.0, 32);
    const double wt3 = ldexp(1.0, 40), wt4 = ldexp(1.0, 48);
#pragma unroll
    for (int mt = 0; mt < 2; ++mt)
#pragma unroll
        for (int nt = 0; nt < 2; ++nt)
#pragma unroll
            for (int r = 0; r < 4; ++r) {
                int row = m0 + wm * 32 + mt * 16 + quad * 4 + r;
                int col = n0 + wn * 32 + nt * 16 + l16;
                double dsum = wt0 * (double)acc[0][mt][nt][r]
                            + wt1 * (double)acc[1][mt][nt][r]
                            + wt2 * (double)acc[2][mt][nt][r]
                            + wt3 * (double)acc[3][mt][nt][r]
                            + wt4 * (double)acc[4][mt][nt][r];
                C[(size_t)row * N + col] =
                    (float)(dsum * xsc[row] * wsc[col] + (double)bias[col]);
            }
}

// ------- V projection from precomputed bf16 hi/lo planes -------
__global__ __launch_bounds__(256) void gemm_v64(
    const short* __restrict__ Ahp, const short* __restrict__ Alp,
    const short* __restrict__ Bhp, const short* __restrict__ Blp,
    const float* __restrict__ bias, float* __restrict__ C)
{
    const int K = 1024, N = 1024;
    __shared__ short Ah[64][40];
    __shared__ short Al[64][40];
    __shared__ short Bh[64][40];
    __shared__ short Bl[64][40];

    const int tid = threadIdx.x, lane = tid & 63, wave = tid >> 6;
    const int wm = wave >> 1, wn = wave & 1;
    const int quad = lane >> 4, l16 = lane & 15;
    const int m0 = blockIdx.y * 64, n0 = blockIdx.x * 64;
    const int srow = tid >> 2, sco = (tid & 3) * 8;
    const size_t aoff = (size_t)(m0 + srow) * K + sco;
    const size_t boff = (size_t)(n0 + srow) * K + sco;

    f4 acc[2][2] = {};
    for (int k0 = 0; k0 < K; k0 += 32) {
        s8v ah = *(const s8v*)(Ahp + aoff + k0);
        s8v al = *(const s8v*)(Alp + aoff + k0);
        s8v bh = *(const s8v*)(Bhp + boff + k0);
        s8v bl = *(const s8v*)(Blp + boff + k0);
        __syncthreads();
        *(s8v*)&Ah[srow][sco] = ah;
        *(s8v*)&Al[srow][sco] = al;
        *(s8v*)&Bh[srow][sco] = bh;
        *(s8v*)&Bl[srow][sco] = bl;
        __syncthreads();

        s8v af[2], afl[2], bf[2], bfl[2];
#pragma unroll
        for (int t = 0; t < 2; ++t) {
            af[t]  = *(s8v*)&Ah[wm * 32 + t * 16 + l16][quad * 8];
            afl[t] = *(s8v*)&Al[wm * 32 + t * 16 + l16][quad * 8];
            bf[t]  = *(s8v*)&Bh[wn * 32 + t * 16 + l16][quad * 8];
            bfl[t] = *(s8v*)&Bl[wn * 32 + t * 16 + l16][quad * 8];
        }
#pragma unroll
        for (int mt = 0; mt < 2; ++mt)
#pragma unroll
            for (int nt = 0; nt < 2; ++nt) {
                acc[mt][nt] = __builtin_amdgcn_mfma_f32_16x16x32_bf16(af[mt],  bf[nt],  acc[mt][nt], 0, 0, 0);
                acc[mt][nt] = __builtin_amdgcn_mfma_f32_16x16x32_bf16(af[mt],  bfl[nt], acc[mt][nt], 0, 0, 0);
                acc[mt][nt] = __builtin_amdgcn_mfma_f32_16x16x32_bf16(afl[mt], bf[nt],  acc[mt][nt], 0, 0, 0);
            }
    }
#pragma unroll
    for (int mt = 0; mt < 2; ++mt)
#pragma unroll
        for (int nt = 0; nt < 2; ++nt)
#pragma unroll
            for (int r = 0; r < 4; ++r) {
                int row = m0 + wm * 32 + mt * 16 + quad * 4 + r;
                int col = n0 + wn * 32 + nt * 16 + l16;
                C[(size_t)row * N + col] = acc[mt][nt][r] + bias[col];
            }
}

// ------- score GEMM: 64x64 tile, bf16 inputs, fp32 out -------
__global__ __launch_bounds__(256) void gemm_score(
    const short* __restrict__ Qh, const short* __restrict__ Kh,
    float* __restrict__ C)
{
    const int K = 1024, N = 2048;
    __shared__ short As[64][40];
    __shared__ short Bs[64][40];
    const int tid = threadIdx.x, lane = tid & 63, wave = tid >> 6;
    const int wm = wave >> 1, wn = wave & 1;
    const int quad = lane >> 4, l16 = lane & 15;
    const int m0 = blockIdx.y * 64, n0 = blockIdx.x * 64;
    const int srow = tid >> 2, sco = (tid & 3) * 8;
    const short* ap = Qh + (size_t)(m0 + srow) * K + sco;
    const short* bp = Kh + (size_t)(n0 + srow) * K + sco;

    f4 acc[2][2] = {};
    for (int k0 = 0; k0 < K; k0 += 32) {
        s8v a8 = *(const s8v*)(ap + k0);
        s8v b8 = *(const s8v*)(bp + k0);
        __syncthreads();
        *(s8v*)&As[srow][sco] = a8;
        *(s8v*)&Bs[srow][sco] = b8;
        __syncthreads();
        s8v af[2], bf[2];
#pragma unroll
        for (int t = 0; t < 2; ++t) {
            af[t] = *(s8v*)&As[wm * 32 + t * 16 + l16][quad * 8];
            bf[t] = *(s8v*)&Bs[wn * 32 + t * 16 + l16][quad * 8];
        }
#pragma unroll
        for (int mt = 0; mt < 2; ++mt)
#pragma unroll
            for (int nt = 0; nt < 2; ++nt)
                acc[mt][nt] = __builtin_amdgcn_mfma_f32_16x16x32_bf16(
                    af[mt], bf[nt], acc[mt][nt], 0, 0, 0);
    }
#pragma unroll
    for (int mt = 0; mt < 2; ++mt)
#pragma unroll
        for (int nt = 0; nt < 2; ++nt)
#pragma unroll
            for (int r = 0; r < 4; ++r) {
                int row = m0 + wm * 32 + mt * 16 + quad * 4 + r;
                int col = n0 + wn * 32 + nt * 16 + l16;
                C[(size_t)row * N + col] = acc[mt][nt][r];
            }
}

// ------- fp32 in-place L2 normalize (fp64 norm accumulation) + bf16 copy -------
__global__ __launch_bounds__(256) void l2norm_f32bf16(
    float* __restrict__ fq, float* __restrict__ fk,
    short* __restrict__ hq, short* __restrict__ hk)
{
    float* f = blockIdx.y ? fk : fq;
    short* h = blockIdx.y ? hk : hq;
    const int row = blockIdx.x;
    const int tid = threadIdx.x;
    float4* p4 = (float4*)(f + (size_t)row * 1024);
    float4 v = p4[tid];
    double s = (double)v.x * v.x + (double)v.y * v.y
             + (double)v.z * v.z + (double)v.w * v.w;
#pragma unroll
    for (int off = 32; off > 0; off >>= 1) s += __shfl_down(s, off);
    __shared__ double ws[5];
    if ((tid & 63) == 0) ws[tid >> 6] = s;
    __syncthreads();
    if (tid == 0) ws[4] = fmax(sqrt(ws[0] + ws[1] + ws[2] + ws[3]), 1e-12);
    __syncthreads();
    const double inv = 1.0 / ws[4];
    float o0 = (float)(v.x * inv), o1 = (float)(v.y * inv);
    float o2 = (float)(v.z * inv), o3 = (float)(v.w * inv);
    float4 o = make_float4(o0, o1, o2, o3);
    p4[tid] = o;
    __align__(8) short hv[4] = {f2bf(o0), f2bf(o1), f2bf(o2), f2bf(o3)};
    *(short4*)&h[(size_t)row * 1024 + tid * 4] = *(short4*)hv;
}

// ------- top-NC selection (register tournament) + fp32-input/fp64-accum rerank
//         (3 candidates per wave, interleaved for MLP) + lane-parallel softmax -------
__global__ __launch_bounds__(256) void topk_route(
    const float*  __restrict__ S,
    const float*  __restrict__ Qf,
    const float*  __restrict__ Kf,
    const float*  __restrict__ Vf,
    float* __restrict__ routes_out,
    float* __restrict__ weights_out,
    float* __restrict__ feat_out,
    int batch)
{
    const int P = 2048, D = 1024;
    __shared__ float  qrow[1024];
    __shared__ float  cval[4 * NC];
    __shared__ int    cidx[4 * NC];
    __shared__ int    sel[NC];
    __shared__ double cscore[NC];
    __shared__ int    topi_s[8];
    __shared__ float  wts[8];

    const int p = blockIdx.x;
    const int tid = threadIdx.x;
    const int lane = tid & 63, wave = tid >> 6;

    // ---- load S row into registers (8 elems/thread), stage fp32 q row into LDS ----
    const float4* sr4 = (const float4*)(S + (size_t)p * P);
    const float4 s0 = sr4[tid];
    const float4 s1 = sr4[tid + 256];
    ((float4*)qrow)[tid] = ((const float4*)(Qf + (size_t)p * D))[tid];

    float v[8] = {s0.x, s0.y, s0.z, s0.w, s1.x, s1.y, s1.z, s1.w};
    int   ji[8];
#pragma unroll
    for (int e = 0; e < 8; ++e) {
        ji[e] = (e < 4) ? (4 * tid + e) : (1024 + 4 * tid + (e - 4));
        if (ji[e] == p) v[e] = -1e30f;   // diagonal mask
    }

    float lv = v[0]; int li = ji[0];
#pragma unroll
    for (int e = 1; e < 8; ++e)
        if (v[e] > lv) { lv = v[e]; li = ji[e]; }

    // ---- per-wave top-NC register tournament (no barriers) ----
    float cv_ = -INFINITY; int ci_ = 0x7fffffff;
#pragma unroll 1
    for (int it = 0; it < NC; ++it) {
        float bv = lv; int bi = li;
#pragma unroll
        for (int off = 32; off > 0; off >>= 1) {
            float ov = __shfl_xor(bv, off);
            int   oi = __shfl_xor(bi, off);
            if (ov > bv || (ov == bv && oi < bi)) { bv = ov; bi = oi; }
        }
        if (lane == it) { cv_ = bv; ci_ = bi; }
#pragma unroll
        for (int e = 0; e < 8; ++e)
            if (ji[e] == bi) v[e] = -INFINITY;
        lv = v[0]; li = ji[0];
#pragma unroll
        for (int e = 1; e < 8; ++e)
            if (v[e] > lv) { lv = v[e]; li = ji[e]; }
    }
    if (lane < NC) { cval[wave * NC + lane] = cv_; cidx[wave * NC + lane] = ci_; }
    __syncthreads();

    // ---- rank-based merge 4*NC -> NC on wave 0 (total order: ties broken by idx,
    //      (val,idx) pairs unique) — identical semantics to iterative merge ----
    if (wave == 0) {
        float mv = (lane < 4 * NC) ? cval[lane] : -INFINITY;
        int   mi = (lane < 4 * NC) ? cidx[lane] : 0x7fffffff;
        int rank = 0;
#pragma unroll 1
        for (int j = 0; j < 4 * NC; ++j) {
            float vj = __shfl(mv, j);
            int   ij = __shfl(mi, j);
            rank += (vj > mv || (vj == mv && ij < mi)) ? 1 : 0;
        }
        if (lane < 4 * NC && rank < NC) sel[rank] = mi;
    }
    __syncthreads();

    // ---- prefetch all NC candidate V rows (every 64B line touched) ----
    float pfv[NC];
#pragma unroll
    for (int c = 0; c < NC; ++c)
        pfv[c] = Vf[(size_t)sel[c] * D + tid * 4];

    // ---- rerank: each wave computes 3 candidates simultaneously (3x MLP) ----
    {
        const float* k0r = Kf + (size_t)sel[wave] * D;
        const float* k1r = Kf + (size_t)sel[wave + 4] * D;
        const float* k2r = Kf + (size_t)sel[wave + 8] * D;
        double a0 = 0.0, a1 = 0.0, a2 = 0.0;
#pragma unroll 4
        for (int j = 0; j < 8; ++j) {
            const int e = lane * 2 + j * 128;
            const float2 q2 = *(const float2*)&qrow[e];
            const float2 kA = *(const float2*)&k0r[e];
            const float2 kB = *(const float2*)&k1r[e];
            const float2 kC = *(const float2*)&k2r[e];
            a0 = fma((double)q2.x, (double)kA.x, fma((double)q2.y, (double)kA.y, a0));
            a1 = fma((double)q2.x, (double)kB.x, fma((double)q2.y, (double)kB.y, a1));
            a2 = fma((double)q2.x, (double)kC.x, fma((double)q2.y, (double)kC.y, a2));
        }
#pragma unroll
        for (int off = 32; off > 0; off >>= 1) {
            a0 += __shfl_xor(a0, off);
            a1 += __shfl_xor(a1, off);
            a2 += __shfl_xor(a2, off);
        }
        if (lane == 0) {
            cscore[wave]     = a0;
            cscore[wave + 4] = a1;
            cscore[wave + 8] = a2;
        }
    }

    // consume prefetch values (keeps loads live; no output effect)
    {
        float pf = 0.f;
#pragma unroll
        for (int c = 0; c < NC; ++c) pf += pfv[c];
        asm volatile("" :: "v"(pf));
    }
    __syncthreads();

    // ---- lane-parallel top-8 of NC + softmax on wave 0 ----
    // rank by (score desc, idx asc); ranks unique (idx unique) => exact
    if (wave == 0) {
        double sc_ = (lane < NC) ? cscore[lane] : -1.0e308;
        int    id_ = (lane < NC) ? sel[lane]    : 0x7fffffff;
        int rank = 0;
#pragma unroll
        for (int j = 0; j < NC; ++j) {
            double vj = __shfl(sc_, j);
            int    ij = __shfl(id_, j);
            rank += (vj > sc_ || (vj == sc_ && ij < id_)) ? 1 : 0;
        }
        double mm = sc_;
#pragma unroll
        for (int off = 32; off > 0; off >>= 1) mm = fmax(mm, __shfl_xor(mm, off));
        double e = (rank < 8 && lane < NC) ? exp((sc_ - mm) / TEMP) : 0.0;
        double sum = e;
#pragma unroll
        for (int off = 32; off > 0; off >>= 1) sum += __shfl_xor(sum, off);
        if (rank < 8 && lane < NC) {
            float wk = (float)(e / sum);
            wts[rank] = wk; topi_s[rank] = id_;
            const size_t row = (size_t)batch * P + p;
            routes_out[row * 8 + rank]  = (float)id_;
            weights_out[row * 8 + rank] = wk;
        }
    }
    __syncthreads();

    // ---- V gather + weighted sum (rows L2-hot from prefetch) ----
    float4 a = {0.f, 0.f, 0.f, 0.f};
#pragma unroll
    for (int k = 0; k < 8; ++k) {
        const float4 v4 = ((const float4*)(Vf + (size_t)topi_s[k] * D))[tid];
        float wk = wts[k];
        a.x = fmaf(wk, v4.x, a.x);
        a.y = fmaf(wk, v4.y, a.y);
        a.z = fmaf(wk, v4.z, a.z);
        a.w = fmaf(wk, v4.w, a.w);
    }
    ((float4*)(feat_out + ((size_t)batch * P + p) * D))[tid] = a;
}

extern "C" void kernel_launch(void* const* d_in, const int* in_sizes, int n_in,
                              void* d_out, int out_size, void* d_ws, size_t ws_size,
                              hipStream_t stream)
{
    const float* x  = (const float*)d_in[0];  // (4,2049,1024)
    const float* Wq = (const float*)d_in[1];
    const float* bq = (const float*)d_in[2];
    const float* Wk = (const float*)d_in[3];
    const float* bk = (const float*)d_in[4];
    const float* Wv = (const float*)d_in[5];
    const float* bv = (const float*)d_in[6];

    const int B = 4, P = 2048, D = 1024;
    const size_t PD = (size_t)P * D;
    const size_t DD = (size_t)D * D;

    float*  Qf   = (float*)d_ws;              // P*D fp32 (projection, then normalized)
    float*  Kf   = Qf + PD;                   // P*D fp32
    double* xsc  = (double*)(Kf + PD);        // 2048
    double* wqsc = xsc + 2048;                // 1024
    double* wksc = wqsc + 1024;               // 1024
    short*  Qh   = (short*)(wksc + 1024);     // P*D bf16
    short*  Kh   = Qh + PD;
    short*  xh   = Kh + PD;                   // x bf16 hi
    short*  xlo  = xh + PD;                   // x bf16 lo
    short*  Wvh  = xlo + PD;                  // Wv bf16 hi
    short*  Wvl  = Wvh + DD;                  // Wv bf16 lo
    float*  Vf   = (float*)(Wvl + DD);        // P*D f32
    float*  Sf   = Vf + PD;                   // P*P f32
    signed char* Xl  = (signed char*)(Sf + (size_t)P * P);  // 4*P*D
    signed char* Wql = Xl + 4 * PD;                          // 4*D*D
    signed char* Wkl = Wql + 4 * DD;

    float* out     = (float*)d_out;
    float* routes  = out;
    float* weights = out + (size_t)B * P * 8;
    float* feat    = out + (size_t)B * P * 16;

    dim3 blk(256);
    quantize_rows<<<dim3(1024), blk, 0, stream>>>(Wq, Wql, (long)DD, wqsc);
    quantize_rows<<<dim3(1024), blk, 0, stream>>>(Wk, Wkl, (long)DD, wksc);
    tobf16_split<<<dim3(1024), blk, 0, stream>>>(Wv, Wvh, Wvl);

    for (int b = 0; b < B; ++b) {
        const float* xb = x + ((size_t)b * 2049 + 1) * D;  // rows 1..2048 contiguous
        prep_x<<<dim3(P), blk, 0, stream>>>(xb, Xl, (long)PD, xsc, xh, xlo);
        gemm_i8qk<<<dim3(16, 32, 2), blk, 0, stream>>>(Xl, Wql, Wkl, xsc, wqsc, wksc,
                                                       bq, bk, Qf, Kf);
        gemm_v64<<<dim3(16, 32), blk, 0, stream>>>(xh, xlo, Wvh, Wvl, bv, Vf);
        l2norm_f32bf16<<<dim3(P, 2), blk, 0, stream>>>(Qf, Kf, Qh, Kh);
        gemm_score<<<dim3(32, 32), blk, 0, stream>>>(Qh, Kh, Sf);
        topk_route<<<dim3(P), blk, 0, stream>>>(Sf, Qf, Kf, Vf, routes, weights, feat, b);
    }
}

// Round 6
// 737.380 us; speedup vs baseline: 1.2867x; 1.0523x over previous
//
#include <hip/hip_runtime.h>
#include <hip/hip_bf16.h>
#include <math.h>

#define TEMP 0.1
#define NC 12   // rerank candidate count (true top-8 ⊂ bf16 top-12: >50-sigma margin)

typedef float f4 __attribute__((ext_vector_type(4)));
typedef short s8v __attribute__((ext_vector_type(8)));
typedef int   i4v __attribute__((ext_vector_type(4)));

__device__ inline short f2bf(float f) {
    __hip_bfloat16 h = __float2bfloat16(f);
    return *reinterpret_cast<short*>(&h);
}
__device__ inline float bf2f(short s) {
    __hip_bfloat16 h = *reinterpret_cast<__hip_bfloat16*>(&s);
    return __bfloat162float(h);
}

// ---------- quantize rows of 1024 to 4 balanced int8 limbs (W setup only) ----------
__global__ __launch_bounds__(256) void quantize_rows(
    const float* __restrict__ src, signed char* __restrict__ limbs,
    long plane_stride, double* __restrict__ scale)
{
    const int row = blockIdx.x, tid = threadIdx.x;
    const float4 v = ((const float4*)(src + (size_t)row * 1024))[tid];
    float m = fmaxf(fmaxf(fabsf(v.x), fabsf(v.y)), fmaxf(fabsf(v.z), fabsf(v.w)));
#pragma unroll
    for (int off = 32; off > 0; off >>= 1) m = fmaxf(m, __shfl_down(m, off));
    __shared__ float wmax[4];
    __shared__ int ssig;
    if ((tid & 63) == 0) wmax[tid >> 6] = m;
    __syncthreads();
    if (tid == 0) {
        float rm = fmaxf(fmaxf(wmax[0], wmax[1]), fmaxf(wmax[2], wmax[3]));
        int sig = (rm > 0.f) ? (29 - ilogbf(rm)) : 0;
        ssig = sig;
        scale[row] = ldexp(1.0, -sig);
    }
    __syncthreads();
    const double s2 = ldexp(1.0, ssig);
    float xs[4] = {v.x, v.y, v.z, v.w};
    signed char out[4][4];
#pragma unroll
    for (int e = 0; e < 4; ++e) {
        long X = __double2ll_rn((double)xs[e] * s2);
#pragma unroll
        for (int l = 0; l < 3; ++l) {
            int d = (int)(((X + 128) & 255) - 128);
            out[l][e] = (signed char)d;
            X = (X - d) >> 8;
        }
        out[3][e] = (signed char)X;
    }
#pragma unroll
    for (int l = 0; l < 4; ++l)
        *(char4*)&limbs[(size_t)l * plane_stride + (size_t)row * 1024 + tid * 4] =
            *(char4*)&out[l][0];
}

// ---------- fp32 -> bf16 hi/lo split planes (Wv setup only) ----------
__global__ __launch_bounds__(256) void tobf16_split(
    const float* __restrict__ src, short* __restrict__ hi, short* __restrict__ lo)
{
    const int row = blockIdx.x, tid = threadIdx.x;
    const float4 v = ((const float4*)(src + (size_t)row * 1024))[tid];
    float xs[4] = {v.x, v.y, v.z, v.w};
    __align__(8) short h[4], l[4];
#pragma unroll
    for (int e = 0; e < 4; ++e) {
        h[e] = f2bf(xs[e]);
        l[e] = f2bf(xs[e] - bf2f(h[e]));
    }
    *(short4*)&hi[(size_t)row * 1024 + tid * 4] = *(short4*)h;
    *(short4*)&lo[(size_t)row * 1024 + tid * 4] = *(short4*)l;
}

// ---------- fused x prep: int8 limb quantize + bf16 hi/lo split (single read of x) ----------
__global__ __launch_bounds__(256) void prep_x(
    const float* __restrict__ src, signed char* __restrict__ limbs,
    long plane_stride, double* __restrict__ scale,
    short* __restrict__ hi, short* __restrict__ lo)
{
    const int row = blockIdx.x, tid = threadIdx.x;
    const float4 v = ((const float4*)(src + (size_t)row * 1024))[tid];
    float m = fmaxf(fmaxf(fabsf(v.x), fabsf(v.y)), fmaxf(fabsf(v.z), fabsf(v.w)));
#pragma unroll
    for (int off = 32; off > 0; off >>= 1) m = fmaxf(m, __shfl_down(m, off));
    __shared__ float wmax[4];
    __shared__ int ssig;
    if ((tid & 63) == 0) wmax[tid >> 6] = m;
    __syncthreads();
    if (tid == 0) {
        float rm = fmaxf(fmaxf(wmax[0], wmax[1]), fmaxf(wmax[2], wmax[3]));
        int sig = (rm > 0.f) ? (29 - ilogbf(rm)) : 0;
        ssig = sig;
        scale[row] = ldexp(1.0, -sig);
    }
    __syncthreads();
    const double s2 = ldexp(1.0, ssig);
    float xs[4] = {v.x, v.y, v.z, v.w};
    signed char out[4][4];
    __align__(8) short h[4], l[4];
#pragma unroll
    for (int e = 0; e < 4; ++e) {
        long X = __double2ll_rn((double)xs[e] * s2);
#pragma unroll
        for (int lmb = 0; lmb < 3; ++lmb) {
            int d = (int)(((X + 128) & 255) - 128);
            out[lmb][e] = (signed char)d;
            X = (X - d) >> 8;
        }
        out[3][e] = (signed char)X;
        h[e] = f2bf(xs[e]);
        l[e] = f2bf(xs[e] - bf2f(h[e]));
    }
#pragma unroll
    for (int lmb = 0; lmb < 4; ++lmb)
        *(char4*)&limbs[(size_t)lmb * plane_stride + (size_t)row * 1024 + tid * 4] =
            *(char4*)&out[lmb][0];
    *(short4*)&hi[(size_t)row * 1024 + tid * 4] = *(short4*)h;
    *(short4*)&lo[(size_t)row * 1024 + tid * 4] = *(short4*)l;
}

// ---------- i8-MFMA projection -> fp32 out; 10 pairs (i+j>=3), 4 levels ----------
// Dropped level-2 pairs: ~1.5e-8 typ (2.9e-6 worst-bound) vs 6e-8 fp32 rounding
// already accepted in Qf/Kf — safe.
// LDS layout: LDS[r][t*16] = global[r][(t ^ swz(r))*16], swz(r) = (r>>1)&3.
// Write: slot t = tid&3 (linear), source chunk t^swz(r) (pre-swizzled global addr).
// Read: chunk c at slot c^swz(r) -> recovers c. Same involution both sides.
__global__ __launch_bounds__(256, 3) void gemm_i8qk(
    const signed char* __restrict__ Xl,
    const signed char* __restrict__ Wql,
    const signed char* __restrict__ Wkl,
    const double* __restrict__ xsc,
    const double* __restrict__ wqsc, const double* __restrict__ wksc,
    const float* __restrict__ bq, const float* __restrict__ bk,
    float* __restrict__ Qf, float* __restrict__ Kf)
{
    const int K = 1024, N = 1024;
    const long MK = 2048L * 1024, NK = 1024L * 1024;
    const signed char* Wl = blockIdx.z ? Wkl : Wql;
    const double* wsc = blockIdx.z ? wksc : wqsc;
    const float* bias = blockIdx.z ? bk : bq;
    float* C = blockIdx.z ? Kf : Qf;

    __shared__ __align__(16) signed char Asm[4][64][64];
    __shared__ __align__(16) signed char Bsm[4][64][64];

    const int tid  = threadIdx.x;
    const int lane = tid & 63, wave = tid >> 6;
    const int wm = wave >> 1, wn = wave & 1;
    const int quad = lane >> 4, l16 = lane & 15;
    const int m0 = blockIdx.y * 64, n0 = blockIdx.x * 64;

    const int srow = tid >> 2;
    const int cswz = ((tid & 3) ^ ((srow >> 1) & 3));      // source chunk for slot tid&3
    const signed char* ap = Xl + (size_t)(m0 + srow) * K + cswz * 16;
    const signed char* bp = Wl + (size_t)(n0 + srow) * K + cswz * 16;

    i4v acc[4][2][2] = {};   // level s = i+j-3

    i4v at[4], bt[4];
#pragma unroll
    for (int l = 0; l < 4; ++l) {
        at[l] = *(const i4v*)(ap + l * MK);
        bt[l] = *(const i4v*)(bp + l * NK);
    }

    // LDS write slot is LINEAR (tid&3); fetched chunk is the swizzled one
    const int wpos = srow * 64 + (tid & 3) * 16;

    for (int k0 = 0; k0 < K; k0 += 64) {
        __syncthreads();
#pragma unroll
        for (int l = 0; l < 4; ++l) {
            *(i4v*)&Asm[l][0][wpos] = at[l];
            *(i4v*)&Bsm[l][0][wpos] = bt[l];
        }
        __syncthreads();

        if (k0 + 64 < K) {
#pragma unroll
            for (int l = 0; l < 4; ++l) {
                at[l] = *(const i4v*)(ap + l * MK + k0 + 64);
                bt[l] = *(const i4v*)(bp + l * NK + k0 + 64);
            }
        }

        i4v bF[4][2];
#pragma unroll
        for (int j = 0; j < 4; ++j)
#pragma unroll
            for (int nt = 0; nt < 2; ++nt) {
                const int R = wn * 32 + nt * 16 + l16;
                bF[j][nt] = *(const i4v*)&Bsm[j][R][(quad ^ ((R >> 1) & 3)) * 16];
            }

#pragma unroll
        for (int i = 0; i < 4; ++i) {
            const int R0 = wm * 32 + l16;
            const int R1 = wm * 32 + 16 + l16;
            i4v a0 = *(const i4v*)&Asm[i][R0][(quad ^ ((R0 >> 1) & 3)) * 16];
            i4v a1 = *(const i4v*)&Asm[i][R1][(quad ^ ((R1 >> 1) & 3)) * 16];
#pragma unroll
            for (int j = 0; j < 4; ++j) {
                if (i + j < 3) continue;
                const int s = i + j - 3;
                acc[s][0][0] = __builtin_amdgcn_mfma_i32_16x16x64_i8(a0, bF[j][0], acc[s][0][0], 0, 0, 0);
                acc[s][0][1] = __builtin_amdgcn_mfma_i32_16x16x64_i8(a0, bF[j][1], acc[s][0][1], 0, 0, 0);
                acc[s][1][0] = __builtin_amdgcn_mfma_i32_16x16x64_i8(a1, bF[j][0], acc[s][1][0], 0, 0, 0);
                acc[s][1][1] = __builtin_amdgcn_mfma_i32_16x16x64_i8(a1, bF[j][1], acc[s][1][1], 0, 0, 0);
            }
        }
    }

    const double wt0 = ldexp(1.0, 24), wt1 = ldexp(1.0, 32);
    const double wt2 = ldexp(1.0, 40), wt3 = ldexp(1.0, 48);
#pragma unroll
    for (int mt = 0; mt < 2; ++mt)
#pragma unroll
        for (int nt = 0; nt < 2; ++nt)
#pragma unroll
            for (int r = 0; r < 4; ++r) {
                int row = m0 + wm * 32 + mt * 16 + quad * 4 + r;
                int col = n0 + wn * 32 + nt * 16 + l16;
                double dsum = wt0 * (double)acc[0][mt][nt][r]
                            + wt1 * (double)acc[1][mt][nt][r]
                            + wt2 * (double)acc[2][mt][nt][r]
                            + wt3 * (double)acc[3][mt][nt][r];
                C[(size_t)row * N + col] =
                    (float)(dsum * xsc[row] * wsc[col] + (double)bias[col]);
            }
}

// ------- V projection from precomputed bf16 hi/lo planes -------
__global__ __launch_bounds__(256) void gemm_v64(
    const short* __restrict__ Ahp, const short* __restrict__ Alp,
    const short* __restrict__ Bhp, const short* __restrict__ Blp,
    const float* __restrict__ bias, float* __restrict__ C)
{
    const int K = 1024, N = 1024;
    __shared__ short Ah[64][40];
    __shared__ short Al[64][40];
    __shared__ short Bh[64][40];
    __shared__ short Bl[64][40];

    const int tid = threadIdx.x, lane = tid & 63, wave = tid >> 6;
    const int wm = wave >> 1, wn = wave & 1;
    const int quad = lane >> 4, l16 = lane & 15;
    const int m0 = blockIdx.y * 64, n0 = blockIdx.x * 64;
    const int srow = tid >> 2, sco = (tid & 3) * 8;
    const size_t aoff = (size_t)(m0 + srow) * K + sco;
    const size_t boff = (size_t)(n0 + srow) * K + sco;

    f4 acc[2][2] = {};
    for (int k0 = 0; k0 < K; k0 += 32) {
        s8v ah = *(const s8v*)(Ahp + aoff + k0);
        s8v al = *(const s8v*)(Alp + aoff + k0);
        s8v bh = *(const s8v*)(Bhp + boff + k0);
        s8v bl = *(const s8v*)(Blp + boff + k0);
        __syncthreads();
        *(s8v*)&Ah[srow][sco] = ah;
        *(s8v*)&Al[srow][sco] = al;
        *(s8v*)&Bh[srow][sco] = bh;
        *(s8v*)&Bl[srow][sco] = bl;
        __syncthreads();

        s8v af[2], afl[2], bf[2], bfl[2];
#pragma unroll
        for (int t = 0; t < 2; ++t) {
            af[t]  = *(s8v*)&Ah[wm * 32 + t * 16 + l16][quad * 8];
            afl[t] = *(s8v*)&Al[wm * 32 + t * 16 + l16][quad * 8];
            bf[t]  = *(s8v*)&Bh[wn * 32 + t * 16 + l16][quad * 8];
            bfl[t] = *(s8v*)&Bl[wn * 32 + t * 16 + l16][quad * 8];
        }
#pragma unroll
        for (int mt = 0; mt < 2; ++mt)
#pragma unroll
            for (int nt = 0; nt < 2; ++nt) {
                acc[mt][nt] = __builtin_amdgcn_mfma_f32_16x16x32_bf16(af[mt],  bf[nt],  acc[mt][nt], 0, 0, 0);
                acc[mt][nt] = __builtin_amdgcn_mfma_f32_16x16x32_bf16(af[mt],  bfl[nt], acc[mt][nt], 0, 0, 0);
                acc[mt][nt] = __builtin_amdgcn_mfma_f32_16x16x32_bf16(afl[mt], bf[nt],  acc[mt][nt], 0, 0, 0);
            }
    }
#pragma unroll
    for (int mt = 0; mt < 2; ++mt)
#pragma unroll
        for (int nt = 0; nt < 2; ++nt)
#pragma unroll
            for (int r = 0; r < 4; ++r) {
                int row = m0 + wm * 32 + mt * 16 + quad * 4 + r;
                int col = n0 + wn * 32 + nt * 16 + l16;
                C[(size_t)row * N + col] = acc[mt][nt][r] + bias[col];
            }
}

// ------- score GEMM: 64x64 tile, bf16 inputs, fp32 out -------
__global__ __launch_bounds__(256) void gemm_score(
    const short* __restrict__ Qh, const short* __restrict__ Kh,
    float* __restrict__ C)
{
    const int K = 1024, N = 2048;
    __shared__ short As[64][40];
    __shared__ short Bs[64][40];
    const int tid = threadIdx.x, lane = tid & 63, wave = tid >> 6;
    const int wm = wave >> 1, wn = wave & 1;
    const int quad = lane >> 4, l16 = lane & 15;
    const int m0 = blockIdx.y * 64, n0 = blockIdx.x * 64;
    const int srow = tid >> 2, sco = (tid & 3) * 8;
    const short* ap = Qh + (size_t)(m0 + srow) * K + sco;
    const short* bp = Kh + (size_t)(n0 + srow) * K + sco;

    f4 acc[2][2] = {};
    for (int k0 = 0; k0 < K; k0 += 32) {
        s8v a8 = *(const s8v*)(ap + k0);
        s8v b8 = *(const s8v*)(bp + k0);
        __syncthreads();
        *(s8v*)&As[srow][sco] = a8;
        *(s8v*)&Bs[srow][sco] = b8;
        __syncthreads();
        s8v af[2], bf[2];
#pragma unroll
        for (int t = 0; t < 2; ++t) {
            af[t] = *(s8v*)&As[wm * 32 + t * 16 + l16][quad * 8];
            bf[t] = *(s8v*)&Bs[wn * 32 + t * 16 + l16][quad * 8];
        }
#pragma unroll
        for (int mt = 0; mt < 2; ++mt)
#pragma unroll
            for (int nt = 0; nt < 2; ++nt)
                acc[mt][nt] = __builtin_amdgcn_mfma_f32_16x16x32_bf16(
                    af[mt], bf[nt], acc[mt][nt], 0, 0, 0);
    }
#pragma unroll
    for (int mt = 0; mt < 2; ++mt)
#pragma unroll
        for (int nt = 0; nt < 2; ++nt)
#pragma unroll
            for (int r = 0; r < 4; ++r) {
                int row = m0 + wm * 32 + mt * 16 + quad * 4 + r;
                int col = n0 + wn * 32 + nt * 16 + l16;
                C[(size_t)row * N + col] = acc[mt][nt][r];
            }
}

// ------- fp32 in-place L2 normalize (fp64 norm accumulation) + bf16 copy -------
__global__ __launch_bounds__(256) void l2norm_f32bf16(
    float* __restrict__ fq, float* __restrict__ fk,
    short* __restrict__ hq, short* __restrict__ hk)
{
    float* f = blockIdx.y ? fk : fq;
    short* h = blockIdx.y ? hk : hq;
    const int row = blockIdx.x;
    const int tid = threadIdx.x;
    float4* p4 = (float4*)(f + (size_t)row * 1024);
    float4 v = p4[tid];
    double s = (double)v.x * v.x + (double)v.y * v.y
             + (double)v.z * v.z + (double)v.w * v.w;
#pragma unroll
    for (int off = 32; off > 0; off >>= 1) s += __shfl_down(s, off);
    __shared__ double ws[5];
    if ((tid & 63) == 0) ws[tid >> 6] = s;
    __syncthreads();
    if (tid == 0) ws[4] = fmax(sqrt(ws[0] + ws[1] + ws[2] + ws[3]), 1e-12);
    __syncthreads();
    const double inv = 1.0 / ws[4];
    float o0 = (float)(v.x * inv), o1 = (float)(v.y * inv);
    float o2 = (float)(v.z * inv), o3 = (float)(v.w * inv);
    float4 o = make_float4(o0, o1, o2, o3);
    p4[tid] = o;
    __align__(8) short hv[4] = {f2bf(o0), f2bf(o1), f2bf(o2), f2bf(o3)};
    *(short4*)&h[(size_t)row * 1024 + tid * 4] = *(short4*)hv;
}

// ------- top-NC selection (register tournament) + fp32-input/fp64-accum rerank
//         (3 candidates per wave, interleaved for MLP) + lane-parallel softmax -------
__global__ __launch_bounds__(256) void topk_route(
    const float*  __restrict__ S,
    const float*  __restrict__ Qf,
    const float*  __restrict__ Kf,
    const float*  __restrict__ Vf,
    float* __restrict__ routes_out,
    float* __restrict__ weights_out,
    float* __restrict__ feat_out,
    int batch)
{
    const int P = 2048, D = 1024;
    __shared__ float  qrow[1024];
    __shared__ float  cval[4 * NC];
    __shared__ int    cidx[4 * NC];
    __shared__ int    sel[NC];
    __shared__ double cscore[NC];
    __shared__ int    topi_s[8];
    __shared__ float  wts[8];

    const int p = blockIdx.x;
    const int tid = threadIdx.x;
    const int lane = tid & 63, wave = tid >> 6;

    // ---- load S row into registers (8 elems/thread), stage fp32 q row into LDS ----
    const float4* sr4 = (const float4*)(S + (size_t)p * P);
    const float4 s0 = sr4[tid];
    const float4 s1 = sr4[tid + 256];
    ((float4*)qrow)[tid] = ((const float4*)(Qf + (size_t)p * D))[tid];

    float v[8] = {s0.x, s0.y, s0.z, s0.w, s1.x, s1.y, s1.z, s1.w};
    int   ji[8];
#pragma unroll
    for (int e = 0; e < 8; ++e) {
        ji[e] = (e < 4) ? (4 * tid + e) : (1024 + 4 * tid + (e - 4));
        if (ji[e] == p) v[e] = -1e30f;   // diagonal mask
    }

    float lv = v[0]; int li = ji[0];
#pragma unroll
    for (int e = 1; e < 8; ++e)
        if (v[e] > lv) { lv = v[e]; li = ji[e]; }

    // ---- per-wave top-NC register tournament (no barriers) ----
    float cv_ = -INFINITY; int ci_ = 0x7fffffff;
#pragma unroll 1
    for (int it = 0; it < NC; ++it) {
        float bv = lv; int bi = li;
#pragma unroll
        for (int off = 32; off > 0; off >>= 1) {
            float ov = __shfl_xor(bv, off);
            int   oi = __shfl_xor(bi, off);
            if (ov > bv || (ov == bv && oi < bi)) { bv = ov; bi = oi; }
        }
        if (lane == it) { cv_ = bv; ci_ = bi; }
#pragma unroll
        for (int e = 0; e < 8; ++e)
            if (ji[e] == bi) v[e] = -INFINITY;
        lv = v[0]; li = ji[0];
#pragma unroll
        for (int e = 1; e < 8; ++e)
            if (v[e] > lv) { lv = v[e]; li = ji[e]; }
    }
    if (lane < NC) { cval[wave * NC + lane] = cv_; cidx[wave * NC + lane] = ci_; }
    __syncthreads();

    // ---- rank-based merge 4*NC -> NC on wave 0 (total order: ties broken by idx,
    //      (val,idx) pairs unique) — identical semantics to iterative merge ----
    if (wave == 0) {
        float mv = (lane < 4 * NC) ? cval[lane] : -INFINITY;
        int   mi = (lane < 4 * NC) ? cidx[lane] : 0x7fffffff;
        int rank = 0;
#pragma unroll 1
        for (int j = 0; j < 4 * NC; ++j) {
            float vj = __shfl(mv, j);
            int   ij = __shfl(mi, j);
            rank += (vj > mv || (vj == mv && ij < mi)) ? 1 : 0;
        }
        if (lane < 4 * NC && rank < NC) sel[rank] = mi;
    }
    __syncthreads();

    // ---- prefetch all NC candidate V rows (every 64B line touched) ----
    float pfv[NC];
#pragma unroll
    for (int c = 0; c < NC; ++c)
        pfv[c] = Vf[(size_t)sel[c] * D + tid * 4];

    // ---- rerank: each wave computes 3 candidates simultaneously (3x MLP) ----
    {
        const float* k0r = Kf + (size_t)sel[wave] * D;
        const float* k1r = Kf + (size_t)sel[wave + 4] * D;
        const float* k2r = Kf + (size_t)sel[wave + 8] * D;
        double a0 = 0.0, a1 = 0.0, a2 = 0.0;
#pragma unroll 4
        for (int j = 0; j < 8; ++j) {
            const int e = lane * 2 + j * 128;
            const float2 q2 = *(const float2*)&qrow[e];
            const float2 kA = *(const float2*)&k0r[e];
            const float2 kB = *(const float2*)&k1r[e];
            const float2 kC = *(const float2*)&k2r[e];
            a0 = fma((double)q2.x, (double)kA.x, fma((double)q2.y, (double)kA.y, a0));
            a1 = fma((double)q2.x, (double)kB.x, fma((double)q2.y, (double)kB.y, a1));
            a2 = fma((double)q2.x, (double)kC.x, fma((double)q2.y, (double)kC.y, a2));
        }
#pragma unroll
        for (int off = 32; off > 0; off >>= 1) {
            a0 += __shfl_xor(a0, off);
            a1 += __shfl_xor(a1, off);
            a2 += __shfl_xor(a2, off);
        }
        if (lane == 0) {
            cscore[wave]     = a0;
            cscore[wave + 4] = a1;
            cscore[wave + 8] = a2;
        }
    }

    // consume prefetch values (keeps loads live; no output effect)
    {
        float pf = 0.f;
#pragma unroll
        for (int c = 0; c < NC; ++c) pf += pfv[c];
        asm volatile("" :: "v"(pf));
    }
    __syncthreads();

    // ---- lane-parallel top-8 of NC + softmax on wave 0 ----
    // rank by (score desc, idx asc); ranks unique (idx unique) => exact
    if (wave == 0) {
        double sc_ = (lane < NC) ? cscore[lane] : -1.0e308;
        int    id_ = (lane < NC) ? sel[lane]    : 0x7fffffff;
        int rank = 0;
#pragma unroll
        for (int j = 0; j < NC; ++j) {
            double vj = __shfl(sc_, j);
            int    ij = __shfl(id_, j);
            rank += (vj > sc_ || (vj == sc_ && ij < id_)) ? 1 : 0;
        }
        double mm = sc_;
#pragma unroll
        for (int off = 32; off > 0; off >>= 1) mm = fmax(mm, __shfl_xor(mm, off));
        double e = (rank < 8 && lane < NC) ? exp((sc_ - mm) / TEMP) : 0.0;
        double sum = e;
#pragma unroll
        for (int off = 32; off > 0; off >>= 1) sum += __shfl_xor(sum, off);
        if (rank < 8 && lane < NC) {
            float wk = (float)(e / sum);
            wts[rank] = wk; topi_s[rank] = id_;
            const size_t row = (size_t)batch * P + p;
            routes_out[row * 8 + rank]  = (float)id_;
            weights_out[row * 8 + rank] = wk;
        }
    }
    __syncthreads();

    // ---- V gather + weighted sum (rows L2-hot from prefetch) ----
    float4 a = {0.f, 0.f, 0.f, 0.f};
#pragma unroll
    for (int k = 0; k < 8; ++k) {
        const float4 v4 = ((const float4*)(Vf + (size_t)topi_s[k] * D))[tid];
        float wk = wts[k];
        a.x = fmaf(wk, v4.x, a.x);
        a.y = fmaf(wk, v4.y, a.y);
        a.z = fmaf(wk, v4.z, a.z);
        a.w = fmaf(wk, v4.w, a.w);
    }
    ((float4*)(feat_out + ((size_t)batch * P + p) * D))[tid] = a;
}

extern "C" void kernel_launch(void* const* d_in, const int* in_sizes, int n_in,
                              void* d_out, int out_size, void* d_ws, size_t ws_size,
                              hipStream_t stream)
{
    const float* x  = (const float*)d_in[0];  // (4,2049,1024)
    const float* Wq = (const float*)d_in[1];
    const float* bq = (const float*)d_in[2];
    const float* Wk = (const float*)d_in[3];
    const float* bk = (const float*)d_in[4];
    const float* Wv = (const float*)d_in[5];
    const float* bv = (const float*)d_in[6];

    const int B = 4, P = 2048, D = 1024;
    const size_t PD = (size_t)P * D;
    const size_t DD = (size_t)D * D;

    float*  Qf   = (float*)d_ws;              // P*D fp32 (projection, then normalized)
    float*  Kf   = Qf + PD;                   // P*D fp32
    double* xsc  = (double*)(Kf + PD);        // 2048
    double* wqsc = xsc + 2048;                // 1024
    double* wksc = wqsc + 1024;               // 1024
    short*  Qh   = (short*)(wksc + 1024);     // P*D bf16
    short*  Kh   = Qh + PD;
    short*  xh   = Kh + PD;                   // x bf16 hi
    short*  xlo  = xh + PD;                   // x bf16 lo
    short*  Wvh  = xlo + PD;                  // Wv bf16 hi
    short*  Wvl  = Wvh + DD;                  // Wv bf16 lo
    float*  Vf   = (float*)(Wvl + DD);        // P*D f32
    float*  Sf   = Vf + PD;                   // P*P f32
    signed char* Xl  = (signed char*)(Sf + (size_t)P * P);  // 4*P*D
    signed char* Wql = Xl + 4 * PD;                          // 4*D*D
    signed char* Wkl = Wql + 4 * DD;

    float* out     = (float*)d_out;
    float* routes  = out;
    float* weights = out + (size_t)B * P * 8;
    float* feat    = out + (size_t)B * P * 16;

    dim3 blk(256);
    quantize_rows<<<dim3(1024), blk, 0, stream>>>(Wq, Wql, (long)DD, wqsc);
    quantize_rows<<<dim3(1024), blk, 0, stream>>>(Wk, Wkl, (long)DD, wksc);
    tobf16_split<<<dim3(1024), blk, 0, stream>>>(Wv, Wvh, Wvl);

    for (int b = 0; b < B; ++b) {
        const float* xb = x + ((size_t)b * 2049 + 1) * D;  // rows 1..2048 contiguous
        prep_x<<<dim3(P), blk, 0, stream>>>(xb, Xl, (long)PD, xsc, xh, xlo);
        gemm_i8qk<<<dim3(16, 32, 2), blk, 0, stream>>>(Xl, Wql, Wkl, xsc, wqsc, wksc,
                                                       bq, bk, Qf, Kf);
        gemm_v64<<<dim3(16, 32), blk, 0, stream>>>(xh, xlo, Wvh, Wvl, bv, Vf);
        l2norm_f32bf16<<<dim3(P, 2), blk, 0, stream>>>(Qf, Kf, Qh, Kh);
        gemm_score<<<dim3(32, 32), blk, 0, stream>>>(Qh, Kh, Sf);
        topk_route<<<dim3(P), blk, 0, stream>>>(Sf, Qf, Kf, Vf, routes, weights, feat, b);
    }
}

// Round 7
// 724.804 us; speedup vs baseline: 1.3090x; 1.0174x over previous
//
#include <hip/hip_runtime.h>
#include <hip/hip_bf16.h>
#include <math.h>

#define TEMP 0.1
#define NC 12   // rerank candidate count (true top-8 ⊂ bf16 top-12: >50-sigma margin)

typedef float f4 __attribute__((ext_vector_type(4)));
typedef short s8v __attribute__((ext_vector_type(8)));
typedef int   i4v __attribute__((ext_vector_type(4)));

__device__ inline short f2bf(float f) {
    __hip_bfloat16 h = __float2bfloat16(f);
    return *reinterpret_cast<short*>(&h);
}
__device__ inline float bf2f(short s) {
    __hip_bfloat16 h = *reinterpret_cast<__hip_bfloat16*>(&s);
    return __bfloat162float(h);
}

// ---------- quantize rows of 1024 to 4 balanced int8 limbs (W setup only) ----------
__global__ __launch_bounds__(256) void quantize_rows(
    const float* __restrict__ src, signed char* __restrict__ limbs,
    long plane_stride, double* __restrict__ scale)
{
    const int row = blockIdx.x, tid = threadIdx.x;
    const float4 v = ((const float4*)(src + (size_t)row * 1024))[tid];
    float m = fmaxf(fmaxf(fabsf(v.x), fabsf(v.y)), fmaxf(fabsf(v.z), fabsf(v.w)));
#pragma unroll
    for (int off = 32; off > 0; off >>= 1) m = fmaxf(m, __shfl_down(m, off));
    __shared__ float wmax[4];
    __shared__ int ssig;
    if ((tid & 63) == 0) wmax[tid >> 6] = m;
    __syncthreads();
    if (tid == 0) {
        float rm = fmaxf(fmaxf(wmax[0], wmax[1]), fmaxf(wmax[2], wmax[3]));
        int sig = (rm > 0.f) ? (29 - ilogbf(rm)) : 0;
        ssig = sig;
        scale[row] = ldexp(1.0, -sig);
    }
    __syncthreads();
    const double s2 = ldexp(1.0, ssig);
    float xs[4] = {v.x, v.y, v.z, v.w};
    signed char out[4][4];
#pragma unroll
    for (int e = 0; e < 4; ++e) {
        long X = __double2ll_rn((double)xs[e] * s2);
#pragma unroll
        for (int l = 0; l < 3; ++l) {
            int d = (int)(((X + 128) & 255) - 128);
            out[l][e] = (signed char)d;
            X = (X - d) >> 8;
        }
        out[3][e] = (signed char)X;
    }
#pragma unroll
    for (int l = 0; l < 4; ++l)
        *(char4*)&limbs[(size_t)l * plane_stride + (size_t)row * 1024 + tid * 4] =
            *(char4*)&out[l][0];
}

// ---------- fp32 -> bf16 cast (Wv setup only; V path is pure bf16 now) ----------
__global__ __launch_bounds__(256) void tobf16(
    const float* __restrict__ src, short* __restrict__ hi)
{
    const int row = blockIdx.x, tid = threadIdx.x;
    const float4 v = ((const float4*)(src + (size_t)row * 1024))[tid];
    __align__(8) short h[4] = {f2bf(v.x), f2bf(v.y), f2bf(v.z), f2bf(v.w)};
    *(short4*)&hi[(size_t)row * 1024 + tid * 4] = *(short4*)h;
}

// ---------- fused x prep: int8 limb quantize + bf16 cast (single read of x) ----------
__global__ __launch_bounds__(256) void prep_x(
    const float* __restrict__ src, signed char* __restrict__ limbs,
    long plane_stride, double* __restrict__ scale,
    short* __restrict__ hi)
{
    const int row = blockIdx.x, tid = threadIdx.x;
    const float4 v = ((const float4*)(src + (size_t)row * 1024))[tid];
    float m = fmaxf(fmaxf(fabsf(v.x), fabsf(v.y)), fmaxf(fabsf(v.z), fabsf(v.w)));
#pragma unroll
    for (int off = 32; off > 0; off >>= 1) m = fmaxf(m, __shfl_down(m, off));
    __shared__ float wmax[4];
    __shared__ int ssig;
    if ((tid & 63) == 0) wmax[tid >> 6] = m;
    __syncthreads();
    if (tid == 0) {
        float rm = fmaxf(fmaxf(wmax[0], wmax[1]), fmaxf(wmax[2], wmax[3]));
        int sig = (rm > 0.f) ? (29 - ilogbf(rm)) : 0;
        ssig = sig;
        scale[row] = ldexp(1.0, -sig);
    }
    __syncthreads();
    const double s2 = ldexp(1.0, ssig);
    float xs[4] = {v.x, v.y, v.z, v.w};
    signed char out[4][4];
    __align__(8) short h[4];
#pragma unroll
    for (int e = 0; e < 4; ++e) {
        long X = __double2ll_rn((double)xs[e] * s2);
#pragma unroll
        for (int lmb = 0; lmb < 3; ++lmb) {
            int d = (int)(((X + 128) & 255) - 128);
            out[lmb][e] = (signed char)d;
            X = (X - d) >> 8;
        }
        out[3][e] = (signed char)X;
        h[e] = f2bf(xs[e]);
    }
#pragma unroll
    for (int lmb = 0; lmb < 4; ++lmb)
        *(char4*)&limbs[(size_t)lmb * plane_stride + (size_t)row * 1024 + tid * 4] =
            *(char4*)&out[lmb][0];
    *(short4*)&hi[(size_t)row * 1024 + tid * 4] = *(short4*)h;
}

// ---------- i8-MFMA projection -> fp32 out; 10 pairs (i+j>=3), 4 levels ----------
// LDS layout: LDS[r][t*16] = global[r][(t ^ swz(r))*16], swz(r) = (r>>1)&3.
// Write slot linear (tid&3), source pre-swizzled; read XORs back. (R6-verified)
__global__ __launch_bounds__(256, 3) void gemm_i8qk(
    const signed char* __restrict__ Xl,
    const signed char* __restrict__ Wql,
    const signed char* __restrict__ Wkl,
    const double* __restrict__ xsc,
    const double* __restrict__ wqsc, const double* __restrict__ wksc,
    const float* __restrict__ bq, const float* __restrict__ bk,
    float* __restrict__ Qf, float* __restrict__ Kf)
{
    const int K = 1024, N = 1024;
    const long MK = 2048L * 1024, NK = 1024L * 1024;
    const signed char* Wl = blockIdx.z ? Wkl : Wql;
    const double* wsc = blockIdx.z ? wksc : wqsc;
    const float* bias = blockIdx.z ? bk : bq;
    float* C = blockIdx.z ? Kf : Qf;

    __shared__ __align__(16) signed char Asm[4][64][64];
    __shared__ __align__(16) signed char Bsm[4][64][64];

    const int tid  = threadIdx.x;
    const int lane = tid & 63, wave = tid >> 6;
    const int wm = wave >> 1, wn = wave & 1;
    const int quad = lane >> 4, l16 = lane & 15;
    const int m0 = blockIdx.y * 64, n0 = blockIdx.x * 64;

    const int srow = tid >> 2;
    const int cswz = ((tid & 3) ^ ((srow >> 1) & 3));      // source chunk for slot tid&3
    const signed char* ap = Xl + (size_t)(m0 + srow) * K + cswz * 16;
    const signed char* bp = Wl + (size_t)(n0 + srow) * K + cswz * 16;

    i4v acc[4][2][2] = {};   // level s = i+j-3

    i4v at[4], bt[4];
#pragma unroll
    for (int l = 0; l < 4; ++l) {
        at[l] = *(const i4v*)(ap + l * MK);
        bt[l] = *(const i4v*)(bp + l * NK);
    }

    const int wpos = srow * 64 + (tid & 3) * 16;

    for (int k0 = 0; k0 < K; k0 += 64) {
        __syncthreads();
#pragma unroll
        for (int l = 0; l < 4; ++l) {
            *(i4v*)&Asm[l][0][wpos] = at[l];
            *(i4v*)&Bsm[l][0][wpos] = bt[l];
        }
        __syncthreads();

        if (k0 + 64 < K) {
#pragma unroll
            for (int l = 0; l < 4; ++l) {
                at[l] = *(const i4v*)(ap + l * MK + k0 + 64);
                bt[l] = *(const i4v*)(bp + l * NK + k0 + 64);
            }
        }

        i4v bF[4][2];
#pragma unroll
        for (int j = 0; j < 4; ++j)
#pragma unroll
            for (int nt = 0; nt < 2; ++nt) {
                const int R = wn * 32 + nt * 16 + l16;
                bF[j][nt] = *(const i4v*)&Bsm[j][R][(quad ^ ((R >> 1) & 3)) * 16];
            }

#pragma unroll
        for (int i = 0; i < 4; ++i) {
            const int R0 = wm * 32 + l16;
            const int R1 = wm * 32 + 16 + l16;
            i4v a0 = *(const i4v*)&Asm[i][R0][(quad ^ ((R0 >> 1) & 3)) * 16];
            i4v a1 = *(const i4v*)&Asm[i][R1][(quad ^ ((R1 >> 1) & 3)) * 16];
#pragma unroll
            for (int j = 0; j < 4; ++j) {
                if (i + j < 3) continue;
                const int s = i + j - 3;
                acc[s][0][0] = __builtin_amdgcn_mfma_i32_16x16x64_i8(a0, bF[j][0], acc[s][0][0], 0, 0, 0);
                acc[s][0][1] = __builtin_amdgcn_mfma_i32_16x16x64_i8(a0, bF[j][1], acc[s][0][1], 0, 0, 0);
                acc[s][1][0] = __builtin_amdgcn_mfma_i32_16x16x64_i8(a1, bF[j][0], acc[s][1][0], 0, 0, 0);
                acc[s][1][1] = __builtin_amdgcn_mfma_i32_16x16x64_i8(a1, bF[j][1], acc[s][1][1], 0, 0, 0);
            }
        }
    }

    const double wt0 = ldexp(1.0, 24), wt1 = ldexp(1.0, 32);
    const double wt2 = ldexp(1.0, 40), wt3 = ldexp(1.0, 48);
#pragma unroll
    for (int mt = 0; mt < 2; ++mt)
#pragma unroll
        for (int nt = 0; nt < 2; ++nt)
#pragma unroll
            for (int r = 0; r < 4; ++r) {
                int row = m0 + wm * 32 + mt * 16 + quad * 4 + r;
                int col = n0 + wn * 32 + nt * 16 + l16;
                double dsum = wt0 * (double)acc[0][mt][nt][r]
                            + wt1 * (double)acc[1][mt][nt][r]
                            + wt2 * (double)acc[2][mt][nt][r]
                            + wt3 * (double)acc[3][mt][nt][r];
                C[(size_t)row * N + col] =
                    (float)(dsum * xsc[row] * wsc[col] + (double)bias[col]);
            }
}

// ------- V projection, pure bf16 single-MFMA (error ~1.8e-2 max on features,
//         ≥8x under strictest per-output threshold; routes/weights unaffected) -------
__global__ __launch_bounds__(256) void gemm_v64(
    const short* __restrict__ Ahp, const short* __restrict__ Bhp,
    const float* __restrict__ bias, float* __restrict__ C)
{
    const int K = 1024, N = 1024;
    __shared__ short Ah[64][40];
    __shared__ short Bh[64][40];

    const int tid = threadIdx.x, lane = tid & 63, wave = tid >> 6;
    const int wm = wave >> 1, wn = wave & 1;
    const int quad = lane >> 4, l16 = lane & 15;
    const int m0 = blockIdx.y * 64, n0 = blockIdx.x * 64;
    const int srow = tid >> 2, sco = (tid & 3) * 8;
    const size_t aoff = (size_t)(m0 + srow) * K + sco;
    const size_t boff = (size_t)(n0 + srow) * K + sco;

    f4 acc[2][2] = {};
    for (int k0 = 0; k0 < K; k0 += 32) {
        s8v ah = *(const s8v*)(Ahp + aoff + k0);
        s8v bh = *(const s8v*)(Bhp + boff + k0);
        __syncthreads();
        *(s8v*)&Ah[srow][sco] = ah;
        *(s8v*)&Bh[srow][sco] = bh;
        __syncthreads();

        s8v af[2], bf[2];
#pragma unroll
        for (int t = 0; t < 2; ++t) {
            af[t] = *(s8v*)&Ah[wm * 32 + t * 16 + l16][quad * 8];
            bf[t] = *(s8v*)&Bh[wn * 32 + t * 16 + l16][quad * 8];
        }
#pragma unroll
        for (int mt = 0; mt < 2; ++mt)
#pragma unroll
            for (int nt = 0; nt < 2; ++nt)
                acc[mt][nt] = __builtin_amdgcn_mfma_f32_16x16x32_bf16(
                    af[mt], bf[nt], acc[mt][nt], 0, 0, 0);
    }
#pragma unroll
    for (int mt = 0; mt < 2; ++mt)
#pragma unroll
        for (int nt = 0; nt < 2; ++nt)
#pragma unroll
            for (int r = 0; r < 4; ++r) {
                int row = m0 + wm * 32 + mt * 16 + quad * 4 + r;
                int col = n0 + wn * 32 + nt * 16 + l16;
                C[(size_t)row * N + col] = acc[mt][nt][r] + bias[col];
            }
}

// ------- score GEMM: 64x64 tile, bf16 inputs, fp32 out -------
__global__ __launch_bounds__(256) void gemm_score(
    const short* __restrict__ Qh, const short* __restrict__ Kh,
    float* __restrict__ C)
{
    const int K = 1024, N = 2048;
    __shared__ short As[64][40];
    __shared__ short Bs[64][40];
    const int tid = threadIdx.x, lane = tid & 63, wave = tid >> 6;
    const int wm = wave >> 1, wn = wave & 1;
    const int quad = lane >> 4, l16 = lane & 15;
    const int m0 = blockIdx.y * 64, n0 = blockIdx.x * 64;
    const int srow = tid >> 2, sco = (tid & 3) * 8;
    const short* ap = Qh + (size_t)(m0 + srow) * K + sco;
    const short* bp = Kh + (size_t)(n0 + srow) * K + sco;

    f4 acc[2][2] = {};
    for (int k0 = 0; k0 < K; k0 += 32) {
        s8v a8 = *(const s8v*)(ap + k0);
        s8v b8 = *(const s8v*)(bp + k0);
        __syncthreads();
        *(s8v*)&As[srow][sco] = a8;
        *(s8v*)&Bs[srow][sco] = b8;
        __syncthreads();
        s8v af[2], bf[2];
#pragma unroll
        for (int t = 0; t < 2; ++t) {
            af[t] = *(s8v*)&As[wm * 32 + t * 16 + l16][quad * 8];
            bf[t] = *(s8v*)&Bs[wn * 32 + t * 16 + l16][quad * 8];
        }
#pragma unroll
        for (int mt = 0; mt < 2; ++mt)
#pragma unroll
            for (int nt = 0; nt < 2; ++nt)
                acc[mt][nt] = __builtin_amdgcn_mfma_f32_16x16x32_bf16(
                    af[mt], bf[nt], acc[mt][nt], 0, 0, 0);
    }
#pragma unroll
    for (int mt = 0; mt < 2; ++mt)
#pragma unroll
        for (int nt = 0; nt < 2; ++nt)
#pragma unroll
            for (int r = 0; r < 4; ++r) {
                int row = m0 + wm * 32 + mt * 16 + quad * 4 + r;
                int col = n0 + wn * 32 + nt * 16 + l16;
                C[(size_t)row * N + col] = acc[mt][nt][r];
            }
}

// ------- fp32 in-place L2 normalize (fp64 norm accumulation) + bf16 copy -------
__global__ __launch_bounds__(256) void l2norm_f32bf16(
    float* __restrict__ fq, float* __restrict__ fk,
    short* __restrict__ hq, short* __restrict__ hk)
{
    float* f = blockIdx.y ? fk : fq;
    short* h = blockIdx.y ? hk : hq;
    const int row = blockIdx.x;
    const int tid = threadIdx.x;
    float4* p4 = (float4*)(f + (size_t)row * 1024);
    float4 v = p4[tid];
    double s = (double)v.x * v.x + (double)v.y * v.y
             + (double)v.z * v.z + (double)v.w * v.w;
#pragma unroll
    for (int off = 32; off > 0; off >>= 1) s += __shfl_down(s, off);
    __shared__ double ws[5];
    if ((tid & 63) == 0) ws[tid >> 6] = s;
    __syncthreads();
    if (tid == 0) ws[4] = fmax(sqrt(ws[0] + ws[1] + ws[2] + ws[3]), 1e-12);
    __syncthreads();
    const double inv = 1.0 / ws[4];
    float o0 = (float)(v.x * inv), o1 = (float)(v.y * inv);
    float o2 = (float)(v.z * inv), o3 = (float)(v.w * inv);
    float4 o = make_float4(o0, o1, o2, o3);
    p4[tid] = o;
    __align__(8) short hv[4] = {f2bf(o0), f2bf(o1), f2bf(o2), f2bf(o3)};
    *(short4*)&h[(size_t)row * 1024 + tid * 4] = *(short4*)hv;
}

// ------- top-NC selection (register tournament) + fp32-input/fp64-accum rerank
//         (3 candidates per wave, interleaved for MLP) + lane-parallel softmax -------
__global__ __launch_bounds__(256) void topk_route(
    const float*  __restrict__ S,
    const float*  __restrict__ Qf,
    const float*  __restrict__ Kf,
    const float*  __restrict__ Vf,
    float* __restrict__ routes_out,
    float* __restrict__ weights_out,
    float* __restrict__ feat_out,
    int batch)
{
    const int P = 2048, D = 1024;
    __shared__ float  qrow[1024];
    __shared__ float  cval[4 * NC];
    __shared__ int    cidx[4 * NC];
    __shared__ int    sel[NC];
    __shared__ double cscore[NC];
    __shared__ int    topi_s[8];
    __shared__ float  wts[8];

    const int p = blockIdx.x;
    const int tid = threadIdx.x;
    const int lane = tid & 63, wave = tid >> 6;

    // ---- load S row into registers (8 elems/thread), stage fp32 q row into LDS ----
    const float4* sr4 = (const float4*)(S + (size_t)p * P);
    const float4 s0 = sr4[tid];
    const float4 s1 = sr4[tid + 256];
    ((float4*)qrow)[tid] = ((const float4*)(Qf + (size_t)p * D))[tid];

    float v[8] = {s0.x, s0.y, s0.z, s0.w, s1.x, s1.y, s1.z, s1.w};
    int   ji[8];
#pragma unroll
    for (int e = 0; e < 8; ++e) {
        ji[e] = (e < 4) ? (4 * tid + e) : (1024 + 4 * tid + (e - 4));
        if (ji[e] == p) v[e] = -1e30f;   // diagonal mask
    }

    float lv = v[0]; int li = ji[0];
#pragma unroll
    for (int e = 1; e < 8; ++e)
        if (v[e] > lv) { lv = v[e]; li = ji[e]; }

    // ---- per-wave top-NC register tournament (no barriers) ----
    float cv_ = -INFINITY; int ci_ = 0x7fffffff;
#pragma unroll 1
    for (int it = 0; it < NC; ++it) {
        float bv = lv; int bi = li;
#pragma unroll
        for (int off = 32; off > 0; off >>= 1) {
            float ov = __shfl_xor(bv, off);
            int   oi = __shfl_xor(bi, off);
            if (ov > bv || (ov == bv && oi < bi)) { bv = ov; bi = oi; }
        }
        if (lane == it) { cv_ = bv; ci_ = bi; }
#pragma unroll
        for (int e = 0; e < 8; ++e)
            if (ji[e] == bi) v[e] = -INFINITY;
        lv = v[0]; li = ji[0];
#pragma unroll
        for (int e = 1; e < 8; ++e)
            if (v[e] > lv) { lv = v[e]; li = ji[e]; }
    }
    if (lane < NC) { cval[wave * NC + lane] = cv_; cidx[wave * NC + lane] = ci_; }
    __syncthreads();

    // ---- rank-based merge 4*NC -> NC on wave 0 (total order: ties broken by idx,
    //      (val,idx) pairs unique) — identical semantics to iterative merge ----
    if (wave == 0) {
        float mv = (lane < 4 * NC) ? cval[lane] : -INFINITY;
        int   mi = (lane < 4 * NC) ? cidx[lane] : 0x7fffffff;
        int rank = 0;
#pragma unroll 1
        for (int j = 0; j < 4 * NC; ++j) {
            float vj = __shfl(mv, j);
            int   ij = __shfl(mi, j);
            rank += (vj > mv || (vj == mv && ij < mi)) ? 1 : 0;
        }
        if (lane < 4 * NC && rank < NC) sel[rank] = mi;
    }
    __syncthreads();

    // ---- prefetch all NC candidate V rows (every 64B line touched) ----
    float pfv[NC];
#pragma unroll
    for (int c = 0; c < NC; ++c)
        pfv[c] = Vf[(size_t)sel[c] * D + tid * 4];

    // ---- rerank: each wave computes 3 candidates simultaneously (3x MLP) ----
    {
        const float* k0r = Kf + (size_t)sel[wave] * D;
        const float* k1r = Kf + (size_t)sel[wave + 4] * D;
        const float* k2r = Kf + (size_t)sel[wave + 8] * D;
        double a0 = 0.0, a1 = 0.0, a2 = 0.0;
#pragma unroll 4
        for (int j = 0; j < 8; ++j) {
            const int e = lane * 2 + j * 128;
            const float2 q2 = *(const float2*)&qrow[e];
            const float2 kA = *(const float2*)&k0r[e];
            const float2 kB = *(const float2*)&k1r[e];
            const float2 kC = *(const float2*)&k2r[e];
            a0 = fma((double)q2.x, (double)kA.x, fma((double)q2.y, (double)kA.y, a0));
            a1 = fma((double)q2.x, (double)kB.x, fma((double)q2.y, (double)kB.y, a1));
            a2 = fma((double)q2.x, (double)kC.x, fma((double)q2.y, (double)kC.y, a2));
        }
#pragma unroll
        for (int off = 32; off > 0; off >>= 1) {
            a0 += __shfl_xor(a0, off);
            a1 += __shfl_xor(a1, off);
            a2 += __shfl_xor(a2, off);
        }
        if (lane == 0) {
            cscore[wave]     = a0;
            cscore[wave + 4] = a1;
            cscore[wave + 8] = a2;
        }
    }

    // consume prefetch values (keeps loads live; no output effect)
    {
        float pf = 0.f;
#pragma unroll
        for (int c = 0; c < NC; ++c) pf += pfv[c];
        asm volatile("" :: "v"(pf));
    }
    __syncthreads();

    // ---- lane-parallel top-8 of NC + softmax on wave 0 ----
    // rank by (score desc, idx asc); ranks unique (idx unique) => exact
    if (wave == 0) {
        double sc_ = (lane < NC) ? cscore[lane] : -1.0e308;
        int    id_ = (lane < NC) ? sel[lane]    : 0x7fffffff;
        int rank = 0;
#pragma unroll
        for (int j = 0; j < NC; ++j) {
            double vj = __shfl(sc_, j);
            int    ij = __shfl(id_, j);
            rank += (vj > sc_ || (vj == sc_ && ij < id_)) ? 1 : 0;
        }
        double mm = sc_;
#pragma unroll
        for (int off = 32; off > 0; off >>= 1) mm = fmax(mm, __shfl_xor(mm, off));
        double e = (rank < 8 && lane < NC) ? exp((sc_ - mm) / TEMP) : 0.0;
        double sum = e;
#pragma unroll
        for (int off = 32; off > 0; off >>= 1) sum += __shfl_xor(sum, off);
        if (rank < 8 && lane < NC) {
            float wk = (float)(e / sum);
            wts[rank] = wk; topi_s[rank] = id_;
            const size_t row = (size_t)batch * P + p;
            routes_out[row * 8 + rank]  = (float)id_;
            weights_out[row * 8 + rank] = wk;
        }
    }
    __syncthreads();

    // ---- V gather + weighted sum (rows L2-hot from prefetch) ----
    float4 a = {0.f, 0.f, 0.f, 0.f};
#pragma unroll
    for (int k = 0; k < 8; ++k) {
        const float4 v4 = ((const float4*)(Vf + (size_t)topi_s[k] * D))[tid];
        float wk = wts[k];
        a.x = fmaf(wk, v4.x, a.x);
        a.y = fmaf(wk, v4.y, a.y);
        a.z = fmaf(wk, v4.z, a.z);
        a.w = fmaf(wk, v4.w, a.w);
    }
    ((float4*)(feat_out + ((size_t)batch * P + p) * D))[tid] = a;
}

extern "C" void kernel_launch(void* const* d_in, const int* in_sizes, int n_in,
                              void* d_out, int out_size, void* d_ws, size_t ws_size,
                              hipStream_t stream)
{
    const float* x  = (const float*)d_in[0];  // (4,2049,1024)
    const float* Wq = (const float*)d_in[1];
    const float* bq = (const float*)d_in[2];
    const float* Wk = (const float*)d_in[3];
    const float* bk = (const float*)d_in[4];
    const float* Wv = (const float*)d_in[5];
    const float* bv = (const float*)d_in[6];

    const int B = 4, P = 2048, D = 1024;
    const size_t PD = (size_t)P * D;
    const size_t DD = (size_t)D * D;

    float*  Qf   = (float*)d_ws;              // P*D fp32 (projection, then normalized)
    float*  Kf   = Qf + PD;                   // P*D fp32
    double* xsc  = (double*)(Kf + PD);        // 2048
    double* wqsc = xsc + 2048;                // 1024
    double* wksc = wqsc + 1024;               // 1024
    short*  Qh   = (short*)(wksc + 1024);     // P*D bf16
    short*  Kh   = Qh + PD;
    short*  xh   = Kh + PD;                   // x bf16
    short*  Wvh  = xh + PD;                   // Wv bf16
    float*  Vf   = (float*)(Wvh + DD);        // P*D f32
    float*  Sf   = Vf + PD;                   // P*P f32
    signed char* Xl  = (signed char*)(Sf + (size_t)P * P);  // 4*P*D
    signed char* Wql = Xl + 4 * PD;                          // 4*D*D
    signed char* Wkl = Wql + 4 * DD;

    float* out     = (float*)d_out;
    float* routes  = out;
    float* weights = out + (size_t)B * P * 8;
    float* feat    = out + (size_t)B * P * 16;

    dim3 blk(256);
    quantize_rows<<<dim3(1024), blk, 0, stream>>>(Wq, Wql, (long)DD, wqsc);
    quantize_rows<<<dim3(1024), blk, 0, stream>>>(Wk, Wkl, (long)DD, wksc);
    tobf16<<<dim3(1024), blk, 0, stream>>>(Wv, Wvh);

    for (int b = 0; b < B; ++b) {
        const float* xb = x + ((size_t)b * 2049 + 1) * D;  // rows 1..2048 contiguous
        prep_x<<<dim3(P), blk, 0, stream>>>(xb, Xl, (long)PD, xsc, xh);
        gemm_i8qk<<<dim3(16, 32, 2), blk, 0, stream>>>(Xl, Wql, Wkl, xsc, wqsc, wksc,
                                                       bq, bk, Qf, Kf);
        gemm_v64<<<dim3(16, 32), blk, 0, stream>>>(xh, Wvh, bv, Vf);
        l2norm_f32bf16<<<dim3(P, 2), blk, 0, stream>>>(Qf, Kf, Qh, Kh);
        gemm_score<<<dim3(32, 32), blk, 0, stream>>>(Qh, Kh, Sf);
        topk_route<<<dim3(P), blk, 0, stream>>>(Sf, Qf, Kf, Vf, routes, weights, feat, b);
    }
}

// Round 8
// 662.679 us; speedup vs baseline: 1.4317x; 1.0937x over previous
//
#include <hip/hip_runtime.h>
#include <hip/hip_bf16.h>
#include <math.h>

#define TEMP 0.1
#define NC 12   // rerank candidate count (true top-8 ⊂ bf16 top-12: >50-sigma margin)

typedef float f4 __attribute__((ext_vector_type(4)));
typedef short s8v __attribute__((ext_vector_type(8)));
typedef int   i4v __attribute__((ext_vector_type(4)));

__device__ inline short f2bf(float f) {
    __hip_bfloat16 h = __float2bfloat16(f);
    return *reinterpret_cast<short*>(&h);
}
__device__ inline float bf2f(short s) {
    __hip_bfloat16 h = *reinterpret_cast<__hip_bfloat16*>(&s);
    return __bfloat162float(h);
}

// 16B global->LDS DMA: global addr is PER-LANE, LDS dest is wave-uniform base,
// HW scatters lane i at base + i*16 (m104/m97 semantics).
__device__ __forceinline__ void g2l16(const void* g, void* l) {
    __builtin_amdgcn_global_load_lds(
        (const __attribute__((address_space(1))) void*)g,
        (__attribute__((address_space(3))) void*)l, 16, 0, 0);
}

// ---------- quantize rows of 1024 to 4 balanced int8 limbs (W setup only) ----------
__global__ __launch_bounds__(256) void quantize_rows(
    const float* __restrict__ src, signed char* __restrict__ limbs,
    long plane_stride, double* __restrict__ scale)
{
    const int row = blockIdx.x, tid = threadIdx.x;
    const float4 v = ((const float4*)(src + (size_t)row * 1024))[tid];
    float m = fmaxf(fmaxf(fabsf(v.x), fabsf(v.y)), fmaxf(fabsf(v.z), fabsf(v.w)));
#pragma unroll
    for (int off = 32; off > 0; off >>= 1) m = fmaxf(m, __shfl_down(m, off));
    __shared__ float wmax[4];
    __shared__ int ssig;
    if ((tid & 63) == 0) wmax[tid >> 6] = m;
    __syncthreads();
    if (tid == 0) {
        float rm = fmaxf(fmaxf(wmax[0], wmax[1]), fmaxf(wmax[2], wmax[3]));
        int sig = (rm > 0.f) ? (29 - ilogbf(rm)) : 0;
        ssig = sig;
        scale[row] = ldexp(1.0, -sig);
    }
    __syncthreads();
    const double s2 = ldexp(1.0, ssig);
    float xs[4] = {v.x, v.y, v.z, v.w};
    signed char out[4][4];
#pragma unroll
    for (int e = 0; e < 4; ++e) {
        long X = __double2ll_rn((double)xs[e] * s2);
#pragma unroll
        for (int l = 0; l < 3; ++l) {
            int d = (int)(((X + 128) & 255) - 128);
            out[l][e] = (signed char)d;
            X = (X - d) >> 8;
        }
        out[3][e] = (signed char)X;
    }
#pragma unroll
    for (int l = 0; l < 4; ++l)
        *(char4*)&limbs[(size_t)l * plane_stride + (size_t)row * 1024 + tid * 4] =
            *(char4*)&out[l][0];
}

// ---------- fp32 -> bf16 cast (Wv setup only) ----------
__global__ __launch_bounds__(256) void tobf16(
    const float* __restrict__ src, short* __restrict__ hi)
{
    const int row = blockIdx.x, tid = threadIdx.x;
    const float4 v = ((const float4*)(src + (size_t)row * 1024))[tid];
    __align__(8) short h[4] = {f2bf(v.x), f2bf(v.y), f2bf(v.z), f2bf(v.w)};
    *(short4*)&hi[(size_t)row * 1024 + tid * 4] = *(short4*)h;
}

// ---------- fused x prep: int8 limb quantize + bf16 cast (single read of x) ----------
__global__ __launch_bounds__(256) void prep_x(
    const float* __restrict__ src, signed char* __restrict__ limbs,
    long plane_stride, double* __restrict__ scale,
    short* __restrict__ hi)
{
    const int row = blockIdx.x, tid = threadIdx.x;
    const float4 v = ((const float4*)(src + (size_t)row * 1024))[tid];
    float m = fmaxf(fmaxf(fabsf(v.x), fabsf(v.y)), fmaxf(fabsf(v.z), fabsf(v.w)));
#pragma unroll
    for (int off = 32; off > 0; off >>= 1) m = fmaxf(m, __shfl_down(m, off));
    __shared__ float wmax[4];
    __shared__ int ssig;
    if ((tid & 63) == 0) wmax[tid >> 6] = m;
    __syncthreads();
    if (tid == 0) {
        float rm = fmaxf(fmaxf(wmax[0], wmax[1]), fmaxf(wmax[2], wmax[3]));
        int sig = (rm > 0.f) ? (29 - ilogbf(rm)) : 0;
        ssig = sig;
        scale[row] = ldexp(1.0, -sig);
    }
    __syncthreads();
    const double s2 = ldexp(1.0, ssig);
    float xs[4] = {v.x, v.y, v.z, v.w};
    signed char out[4][4];
    __align__(8) short h[4];
#pragma unroll
    for (int e = 0; e < 4; ++e) {
        long X = __double2ll_rn((double)xs[e] * s2);
#pragma unroll
        for (int lmb = 0; lmb < 3; ++lmb) {
            int d = (int)(((X + 128) & 255) - 128);
            out[lmb][e] = (signed char)d;
            X = (X - d) >> 8;
        }
        out[3][e] = (signed char)X;
        h[e] = f2bf(xs[e]);
    }
#pragma unroll
    for (int lmb = 0; lmb < 4; ++lmb)
        *(char4*)&limbs[(size_t)lmb * plane_stride + (size_t)row * 1024 + tid * 4] =
            *(char4*)&out[lmb][0];
    *(short4*)&hi[(size_t)row * 1024 + tid * 4] = *(short4*)h;
}

// ---------- i8-MFMA projection -> fp32 out; 10 pairs (i+j>=3), 4 levels ----------
// Staging via global_load_lds width-16: LDS dest linear (lane*16), global source
// pre-swizzled (chunk (tid&3)^swz(srow)); read XORs back (R6-verified involution).
__global__ __launch_bounds__(256, 4) void gemm_i8qk(
    const signed char* __restrict__ Xl,
    const signed char* __restrict__ Wql,
    const signed char* __restrict__ Wkl,
    const double* __restrict__ xsc,
    const double* __restrict__ wqsc, const double* __restrict__ wksc,
    const float* __restrict__ bq, const float* __restrict__ bk,
    float* __restrict__ Qf, float* __restrict__ Kf)
{
    const int K = 1024, N = 1024;
    const long MK = 2048L * 1024, NK = 1024L * 1024;
    const signed char* Wl = blockIdx.z ? Wkl : Wql;
    const double* wsc = blockIdx.z ? wksc : wqsc;
    const float* bias = blockIdx.z ? bk : bq;
    float* C = blockIdx.z ? Kf : Qf;

    __shared__ __align__(16) signed char Asm[4][64][64];
    __shared__ __align__(16) signed char Bsm[4][64][64];

    const int tid  = threadIdx.x;
    const int lane = tid & 63, wave = tid >> 6;
    const int wm = wave >> 1, wn = wave & 1;
    const int quad = lane >> 4, l16 = lane & 15;
    const int m0 = blockIdx.y * 64, n0 = blockIdx.x * 64;

    const int srow = tid >> 2;
    const int cswz = ((tid & 3) ^ ((srow >> 1) & 3));      // source chunk for slot tid&3
    const signed char* ap = Xl + (size_t)(m0 + srow) * K + cswz * 16;
    const signed char* bp = Wl + (size_t)(n0 + srow) * K + cswz * 16;

    // wave-uniform LDS bases (lane*16 added by HW => flat offset tid*16 = linear slot)
    signed char* aw = (signed char*)Asm + (wave << 10);
    signed char* bw = (signed char*)Bsm + (wave << 10);

    i4v acc[4][2][2] = {};   // level s = i+j-3

    for (int k0 = 0; k0 < K; k0 += 64) {
        __syncthreads();     // all waves done reading previous tile
#pragma unroll
        for (int l = 0; l < 4; ++l) {
            g2l16(ap + l * MK + k0, aw + l * 4096);
            g2l16(bp + l * NK + k0, bw + l * 4096);
        }
        __syncthreads();     // drains vmcnt -> tile resident

        i4v bF[4][2];
#pragma unroll
        for (int j = 0; j < 4; ++j)
#pragma unroll
            for (int nt = 0; nt < 2; ++nt) {
                const int R = wn * 32 + nt * 16 + l16;
                bF[j][nt] = *(const i4v*)&Bsm[j][R][(quad ^ ((R >> 1) & 3)) * 16];
            }

#pragma unroll
        for (int i = 0; i < 4; ++i) {
            const int R0 = wm * 32 + l16;
            const int R1 = wm * 32 + 16 + l16;
            i4v a0 = *(const i4v*)&Asm[i][R0][(quad ^ ((R0 >> 1) & 3)) * 16];
            i4v a1 = *(const i4v*)&Asm[i][R1][(quad ^ ((R1 >> 1) & 3)) * 16];
#pragma unroll
            for (int j = 0; j < 4; ++j) {
                if (i + j < 3) continue;
                const int s = i + j - 3;
                acc[s][0][0] = __builtin_amdgcn_mfma_i32_16x16x64_i8(a0, bF[j][0], acc[s][0][0], 0, 0, 0);
                acc[s][0][1] = __builtin_amdgcn_mfma_i32_16x16x64_i8(a0, bF[j][1], acc[s][0][1], 0, 0, 0);
                acc[s][1][0] = __builtin_amdgcn_mfma_i32_16x16x64_i8(a1, bF[j][0], acc[s][1][0], 0, 0, 0);
                acc[s][1][1] = __builtin_amdgcn_mfma_i32_16x16x64_i8(a1, bF[j][1], acc[s][1][1], 0, 0, 0);
            }
        }
    }

    const double wt0 = ldexp(1.0, 24), wt1 = ldexp(1.0, 32);
    const double wt2 = ldexp(1.0, 40), wt3 = ldexp(1.0, 48);
#pragma unroll
    for (int mt = 0; mt < 2; ++mt)
#pragma unroll
        for (int nt = 0; nt < 2; ++nt)
#pragma unroll
            for (int r = 0; r < 4; ++r) {
                int row = m0 + wm * 32 + mt * 16 + quad * 4 + r;
                int col = n0 + wn * 32 + nt * 16 + l16;
                double dsum = wt0 * (double)acc[0][mt][nt][r]
                            + wt1 * (double)acc[1][mt][nt][r]
                            + wt2 * (double)acc[2][mt][nt][r]
                            + wt3 * (double)acc[3][mt][nt][r];
                C[(size_t)row * N + col] =
                    (float)(dsum * xsc[row] * wsc[col] + (double)bias[col]);
            }
}

// ------- V projection, pure bf16 single-MFMA; gload_lds staging + swizzle -------
__global__ __launch_bounds__(256, 4) void gemm_v64(
    const short* __restrict__ Ahp, const short* __restrict__ Bhp,
    const float* __restrict__ bias, float* __restrict__ C)
{
    const int K = 1024, N = 1024;
    __shared__ __align__(16) short Ah[64][32];   // rows of 64B = 4 x 16B chunks
    __shared__ __align__(16) short Bh[64][32];

    const int tid = threadIdx.x, lane = tid & 63, wave = tid >> 6;
    const int wm = wave >> 1, wn = wave & 1;
    const int quad = lane >> 4, l16 = lane & 15;
    const int m0 = blockIdx.y * 64, n0 = blockIdx.x * 64;
    const int srow = tid >> 2;
    const int cswz = ((tid & 3) ^ ((srow >> 1) & 3));
    const char* ap = (const char*)(Ahp + (size_t)(m0 + srow) * K) + cswz * 16;
    const char* bp = (const char*)(Bhp + (size_t)(n0 + srow) * K) + cswz * 16;
    char* aw = (char*)Ah + (wave << 10);
    char* bw = (char*)Bh + (wave << 10);

    f4 acc[2][2] = {};
    for (int k0 = 0; k0 < K; k0 += 32) {      // k0 in shorts; 64B/row/iter
        __syncthreads();
        g2l16(ap + 2 * k0, aw);
        g2l16(bp + 2 * k0, bw);
        __syncthreads();

        s8v af[2], bf[2];
#pragma unroll
        for (int t = 0; t < 2; ++t) {
            const int Ra = wm * 32 + t * 16 + l16;
            const int Rb = wn * 32 + t * 16 + l16;
            af[t] = *(const s8v*)((const char*)Ah + Ra * 64 + ((quad ^ ((Ra >> 1) & 3)) << 4));
            bf[t] = *(const s8v*)((const char*)Bh + Rb * 64 + ((quad ^ ((Rb >> 1) & 3)) << 4));
        }
#pragma unroll
        for (int mt = 0; mt < 2; ++mt)
#pragma unroll
            for (int nt = 0; nt < 2; ++nt)
                acc[mt][nt] = __builtin_amdgcn_mfma_f32_16x16x32_bf16(
                    af[mt], bf[nt], acc[mt][nt], 0, 0, 0);
    }
#pragma unroll
    for (int mt = 0; mt < 2; ++mt)
#pragma unroll
        for (int nt = 0; nt < 2; ++nt)
#pragma unroll
            for (int r = 0; r < 4; ++r) {
                int row = m0 + wm * 32 + mt * 16 + quad * 4 + r;
                int col = n0 + wn * 32 + nt * 16 + l16;
                C[(size_t)row * N + col] = acc[mt][nt][r] + bias[col];
            }
}

// ------- score GEMM: 64x64 tile, bf16, gload_lds staging + swizzle -------
__global__ __launch_bounds__(256, 4) void gemm_score(
    const short* __restrict__ Qh, const short* __restrict__ Kh,
    float* __restrict__ C)
{
    const int K = 1024, N = 2048;
    __shared__ __align__(16) short As[64][32];
    __shared__ __align__(16) short Bs[64][32];
    const int tid = threadIdx.x, lane = tid & 63, wave = tid >> 6;
    const int wm = wave >> 1, wn = wave & 1;
    const int quad = lane >> 4, l16 = lane & 15;
    const int m0 = blockIdx.y * 64, n0 = blockIdx.x * 64;
    const int srow = tid >> 2;
    const int cswz = ((tid & 3) ^ ((srow >> 1) & 3));
    const char* ap = (const char*)(Qh + (size_t)(m0 + srow) * K) + cswz * 16;
    const char* bp = (const char*)(Kh + (size_t)(n0 + srow) * K) + cswz * 16;
    char* aw = (char*)As + (wave << 10);
    char* bw = (char*)Bs + (wave << 10);

    f4 acc[2][2] = {};
    for (int k0 = 0; k0 < K; k0 += 32) {
        __syncthreads();
        g2l16(ap + 2 * k0, aw);
        g2l16(bp + 2 * k0, bw);
        __syncthreads();

        s8v af[2], bf[2];
#pragma unroll
        for (int t = 0; t < 2; ++t) {
            const int Ra = wm * 32 + t * 16 + l16;
            const int Rb = wn * 32 + t * 16 + l16;
            af[t] = *(const s8v*)((const char*)As + Ra * 64 + ((quad ^ ((Ra >> 1) & 3)) << 4));
            bf[t] = *(const s8v*)((const char*)Bs + Rb * 64 + ((quad ^ ((Rb >> 1) & 3)) << 4));
        }
#pragma unroll
        for (int mt = 0; mt < 2; ++mt)
#pragma unroll
            for (int nt = 0; nt < 2; ++nt)
                acc[mt][nt] = __builtin_amdgcn_mfma_f32_16x16x32_bf16(
                    af[mt], bf[nt], acc[mt][nt], 0, 0, 0);
    }
#pragma unroll
    for (int mt = 0; mt < 2; ++mt)
#pragma unroll
        for (int nt = 0; nt < 2; ++nt)
#pragma unroll
            for (int r = 0; r < 4; ++r) {
                int row = m0 + wm * 32 + mt * 16 + quad * 4 + r;
                int col = n0 + wn * 32 + nt * 16 + l16;
                C[(size_t)row * N + col] = acc[mt][nt][r];
            }
}

// ------- fp32 in-place L2 normalize (fp64 norm accumulation) + bf16 copy -------
__global__ __launch_bounds__(256) void l2norm_f32bf16(
    float* __restrict__ fq, float* __restrict__ fk,
    short* __restrict__ hq, short* __restrict__ hk)
{
    float* f = blockIdx.y ? fk : fq;
    short* h = blockIdx.y ? hk : hq;
    const int row = blockIdx.x;
    const int tid = threadIdx.x;
    float4* p4 = (float4*)(f + (size_t)row * 1024);
    float4 v = p4[tid];
    double s = (double)v.x * v.x + (double)v.y * v.y
             + (double)v.z * v.z + (double)v.w * v.w;
#pragma unroll
    for (int off = 32; off > 0; off >>= 1) s += __shfl_down(s, off);
    __shared__ double ws[5];
    if ((tid & 63) == 0) ws[tid >> 6] = s;
    __syncthreads();
    if (tid == 0) ws[4] = fmax(sqrt(ws[0] + ws[1] + ws[2] + ws[3]), 1e-12);
    __syncthreads();
    const double inv = 1.0 / ws[4];
    float o0 = (float)(v.x * inv), o1 = (float)(v.y * inv);
    float o2 = (float)(v.z * inv), o3 = (float)(v.w * inv);
    float4 o = make_float4(o0, o1, o2, o3);
    p4[tid] = o;
    __align__(8) short hv[4] = {f2bf(o0), f2bf(o1), f2bf(o2), f2bf(o3)};
    *(short4*)&h[(size_t)row * 1024 + tid * 4] = *(short4*)hv;
}

// ------- top-NC selection (register tournament) + fp32-input/fp64-accum rerank
//         (3 candidates per wave, interleaved for MLP) + lane-parallel softmax -------
__global__ __launch_bounds__(256) void topk_route(
    const float*  __restrict__ S,
    const float*  __restrict__ Qf,
    const float*  __restrict__ Kf,
    const float*  __restrict__ Vf,
    float* __restrict__ routes_out,
    float* __restrict__ weights_out,
    float* __restrict__ feat_out,
    int batch)
{
    const int P = 2048, D = 1024;
    __shared__ float  qrow[1024];
    __shared__ float  cval[4 * NC];
    __shared__ int    cidx[4 * NC];
    __shared__ int    sel[NC];
    __shared__ double cscore[NC];
    __shared__ int    topi_s[8];
    __shared__ float  wts[8];

    const int p = blockIdx.x;
    const int tid = threadIdx.x;
    const int lane = tid & 63, wave = tid >> 6;

    // ---- load S row into registers (8 elems/thread), stage fp32 q row into LDS ----
    const float4* sr4 = (const float4*)(S + (size_t)p * P);
    const float4 s0 = sr4[tid];
    const float4 s1 = sr4[tid + 256];
    ((float4*)qrow)[tid] = ((const float4*)(Qf + (size_t)p * D))[tid];

    float v[8] = {s0.x, s0.y, s0.z, s0.w, s1.x, s1.y, s1.z, s1.w};
    int   ji[8];
#pragma unroll
    for (int e = 0; e < 8; ++e) {
        ji[e] = (e < 4) ? (4 * tid + e) : (1024 + 4 * tid + (e - 4));
        if (ji[e] == p) v[e] = -1e30f;   // diagonal mask
    }

    float lv = v[0]; int li = ji[0];
#pragma unroll
    for (int e = 1; e < 8; ++e)
        if (v[e] > lv) { lv = v[e]; li = ji[e]; }

    // ---- per-wave top-NC register tournament (no barriers) ----
    float cv_ = -INFINITY; int ci_ = 0x7fffffff;
#pragma unroll 1
    for (int it = 0; it < NC; ++it) {
        float bv = lv; int bi = li;
#pragma unroll
        for (int off = 32; off > 0; off >>= 1) {
            float ov = __shfl_xor(bv, off);
            int   oi = __shfl_xor(bi, off);
            if (ov > bv || (ov == bv && oi < bi)) { bv = ov; bi = oi; }
        }
        if (lane == it) { cv_ = bv; ci_ = bi; }
#pragma unroll
        for (int e = 0; e < 8; ++e)
            if (ji[e] == bi) v[e] = -INFINITY;
        lv = v[0]; li = ji[0];
#pragma unroll
        for (int e = 1; e < 8; ++e)
            if (v[e] > lv) { lv = v[e]; li = ji[e]; }
    }
    if (lane < NC) { cval[wave * NC + lane] = cv_; cidx[wave * NC + lane] = ci_; }
    __syncthreads();

    // ---- rank-based merge 4*NC -> NC on wave 0 ----
    if (wave == 0) {
        float mv = (lane < 4 * NC) ? cval[lane] : -INFINITY;
        int   mi = (lane < 4 * NC) ? cidx[lane] : 0x7fffffff;
        int rank = 0;
#pragma unroll 1
        for (int j = 0; j < 4 * NC; ++j) {
            float vj = __shfl(mv, j);
            int   ij = __shfl(mi, j);
            rank += (vj > mv || (vj == mv && ij < mi)) ? 1 : 0;
        }
        if (lane < 4 * NC && rank < NC) sel[rank] = mi;
    }
    __syncthreads();

    // ---- prefetch all NC candidate V rows (every 64B line touched) ----
    float pfv[NC];
#pragma unroll
    for (int c = 0; c < NC; ++c)
        pfv[c] = Vf[(size_t)sel[c] * D + tid * 4];

    // ---- rerank: each wave computes 3 candidates simultaneously (3x MLP) ----
    {
        const float* k0r = Kf + (size_t)sel[wave] * D;
        const float* k1r = Kf + (size_t)sel[wave + 4] * D;
        const float* k2r = Kf + (size_t)sel[wave + 8] * D;
        double a0 = 0.0, a1 = 0.0, a2 = 0.0;
#pragma unroll 4
        for (int j = 0; j < 8; ++j) {
            const int e = lane * 2 + j * 128;
            const float2 q2 = *(const float2*)&qrow[e];
            const float2 kA = *(const float2*)&k0r[e];
            const float2 kB = *(const float2*)&k1r[e];
            const float2 kC = *(const float2*)&k2r[e];
            a0 = fma((double)q2.x, (double)kA.x, fma((double)q2.y, (double)kA.y, a0));
            a1 = fma((double)q2.x, (double)kB.x, fma((double)q2.y, (double)kB.y, a1));
            a2 = fma((double)q2.x, (double)kC.x, fma((double)q2.y, (double)kC.y, a2));
        }
#pragma unroll
        for (int off = 32; off > 0; off >>= 1) {
            a0 += __shfl_xor(a0, off);
            a1 += __shfl_xor(a1, off);
            a2 += __shfl_xor(a2, off);
        }
        if (lane == 0) {
            cscore[wave]     = a0;
            cscore[wave + 4] = a1;
            cscore[wave + 8] = a2;
        }
    }

    // consume prefetch values (keeps loads live; no output effect)
    {
        float pf = 0.f;
#pragma unroll
        for (int c = 0; c < NC; ++c) pf += pfv[c];
        asm volatile("" :: "v"(pf));
    }
    __syncthreads();

    // ---- lane-parallel top-8 of NC + softmax on wave 0 ----
    if (wave == 0) {
        double sc_ = (lane < NC) ? cscore[lane] : -1.0e308;
        int    id_ = (lane < NC) ? sel[lane]    : 0x7fffffff;
        int rank = 0;
#pragma unroll
        for (int j = 0; j < NC; ++j) {
            double vj = __shfl(sc_, j);
            int    ij = __shfl(id_, j);
            rank += (vj > sc_ || (vj == sc_ && ij < id_)) ? 1 : 0;
        }
        double mm = sc_;
#pragma unroll
        for (int off = 32; off > 0; off >>= 1) mm = fmax(mm, __shfl_xor(mm, off));
        double e = (rank < 8 && lane < NC) ? exp((sc_ - mm) / TEMP) : 0.0;
        double sum = e;
#pragma unroll
        for (int off = 32; off > 0; off >>= 1) sum += __shfl_xor(sum, off);
        if (rank < 8 && lane < NC) {
            float wk = (float)(e / sum);
            wts[rank] = wk; topi_s[rank] = id_;
            const size_t row = (size_t)batch * P + p;
            routes_out[row * 8 + rank]  = (float)id_;
            weights_out[row * 8 + rank] = wk;
        }
    }
    __syncthreads();

    // ---- V gather + weighted sum (rows L2-hot from prefetch) ----
    float4 a = {0.f, 0.f, 0.f, 0.f};
#pragma unroll
    for (int k = 0; k < 8; ++k) {
        const float4 v4 = ((const float4*)(Vf + (size_t)topi_s[k] * D))[tid];
        float wk = wts[k];
        a.x = fmaf(wk, v4.x, a.x);
        a.y = fmaf(wk, v4.y, a.y);
        a.z = fmaf(wk, v4.z, a.z);
        a.w = fmaf(wk, v4.w, a.w);
    }
    ((float4*)(feat_out + ((size_t)batch * P + p) * D))[tid] = a;
}

extern "C" void kernel_launch(void* const* d_in, const int* in_sizes, int n_in,
                              void* d_out, int out_size, void* d_ws, size_t ws_size,
                              hipStream_t stream)
{
    const float* x  = (const float*)d_in[0];  // (4,2049,1024)
    const float* Wq = (const float*)d_in[1];
    const float* bq = (const float*)d_in[2];
    const float* Wk = (const float*)d_in[3];
    const float* bk = (const float*)d_in[4];
    const float* Wv = (const float*)d_in[5];
    const float* bv = (const float*)d_in[6];

    const int B = 4, P = 2048, D = 1024;
    const size_t PD = (size_t)P * D;
    const size_t DD = (size_t)D * D;

    float*  Qf   = (float*)d_ws;              // P*D fp32 (projection, then normalized)
    float*  Kf   = Qf + PD;                   // P*D fp32
    double* xsc  = (double*)(Kf + PD);        // 2048
    double* wqsc = xsc + 2048;                // 1024
    double* wksc = wqsc + 1024;               // 1024
    short*  Qh   = (short*)(wksc + 1024);     // P*D bf16
    short*  Kh   = Qh + PD;
    short*  xh   = Kh + PD;                   // x bf16
    short*  Wvh  = xh + PD;                   // Wv bf16
    float*  Vf   = (float*)(Wvh + DD);        // P*D f32
    float*  Sf   = Vf + PD;                   // P*P f32
    signed char* Xl  = (signed char*)(Sf + (size_t)P * P);  // 4*P*D
    signed char* Wql = Xl + 4 * PD;                          // 4*D*D
    signed char* Wkl = Wql + 4 * DD;

    float* out     = (float*)d_out;
    float* routes  = out;
    float* weights = out + (size_t)B * P * 8;
    float* feat    = out + (size_t)B * P * 16;

    dim3 blk(256);
    quantize_rows<<<dim3(1024), blk, 0, stream>>>(Wq, Wql, (long)DD, wqsc);
    quantize_rows<<<dim3(1024), blk, 0, stream>>>(Wk, Wkl, (long)DD, wksc);
    tobf16<<<dim3(1024), blk, 0, stream>>>(Wv, Wvh);

    for (int b = 0; b < B; ++b) {
        const float* xb = x + ((size_t)b * 2049 + 1) * D;  // rows 1..2048 contiguous
        prep_x<<<dim3(P), blk, 0, stream>>>(xb, Xl, (long)PD, xsc, xh);
        gemm_i8qk<<<dim3(16, 32, 2), blk, 0, stream>>>(Xl, Wql, Wkl, xsc, wqsc, wksc,
                                                       bq, bk, Qf, Kf);
        gemm_v64<<<dim3(16, 32), blk, 0, stream>>>(xh, Wvh, bv, Vf);
        l2norm_f32bf16<<<dim3(P, 2), blk, 0, stream>>>(Qf, Kf, Qh, Kh);
        gemm_score<<<dim3(32, 32), blk, 0, stream>>>(Qh, Kh, Sf);
        topk_route<<<dim3(P), blk, 0, stream>>>(Sf, Qf, Kf, Vf, routes, weights, feat, b);
    }
}

// Round 9
// 630.424 us; speedup vs baseline: 1.5049x; 1.0512x over previous
//
#include <hip/hip_runtime.h>
#include <hip/hip_bf16.h>
#include <math.h>

#define TEMP 0.1
#define NC 10   // rerank candidates (true top-8 ⊂ fp16-score top-10; see margin model R9)

typedef float f4 __attribute__((ext_vector_type(4)));
typedef short s8v __attribute__((ext_vector_type(8)));
typedef int   i4v __attribute__((ext_vector_type(4)));
typedef _Float16 h8v __attribute__((ext_vector_type(8)));

__device__ inline short f2bf(float f) {
    __hip_bfloat16 h = __float2bfloat16(f);
    return *reinterpret_cast<short*>(&h);
}

// 16B global->LDS DMA: per-lane global addr, wave-uniform LDS base (+lane*16 by HW).
__device__ __forceinline__ void g2l16(const void* g, void* l) {
    __builtin_amdgcn_global_load_lds(
        (const __attribute__((address_space(1))) void*)g,
        (__attribute__((address_space(3))) void*)l, 16, 0, 0);
}

// ---------- W setup, fused: y=0 quant Wq, y=1 quant Wk, y=2 bf16-cast Wv ----------
__global__ __launch_bounds__(256) void prep_w(
    const float* __restrict__ Wq, const float* __restrict__ Wk,
    const float* __restrict__ Wv,
    signed char* __restrict__ Wql, signed char* __restrict__ Wkl,
    double* __restrict__ wqsc, double* __restrict__ wksc,
    short* __restrict__ Wvh)
{
    const int row = blockIdx.x, tid = threadIdx.x;
    const int which = blockIdx.y;
    if (which == 2) {
        const float4 v = ((const float4*)(Wv + (size_t)row * 1024))[tid];
        __align__(8) short h[4] = {f2bf(v.x), f2bf(v.y), f2bf(v.z), f2bf(v.w)};
        *(short4*)&Wvh[(size_t)row * 1024 + tid * 4] = *(short4*)h;
        return;
    }
    const float* src = which ? Wk : Wq;
    signed char* limbs = which ? Wkl : Wql;
    double* scale = which ? wksc : wqsc;
    const long plane_stride = 1024L * 1024;

    const float4 v = ((const float4*)(src + (size_t)row * 1024))[tid];
    float m = fmaxf(fmaxf(fabsf(v.x), fabsf(v.y)), fmaxf(fabsf(v.z), fabsf(v.w)));
#pragma unroll
    for (int off = 32; off > 0; off >>= 1) m = fmaxf(m, __shfl_down(m, off));
    __shared__ float wmax[4];
    __shared__ int ssig;
    if ((tid & 63) == 0) wmax[tid >> 6] = m;
    __syncthreads();
    if (tid == 0) {
        float rm = fmaxf(fmaxf(wmax[0], wmax[1]), fmaxf(wmax[2], wmax[3]));
        int sig = (rm > 0.f) ? (29 - ilogbf(rm)) : 0;
        ssig = sig;
        scale[row] = ldexp(1.0, -sig);
    }
    __syncthreads();
    const double s2 = ldexp(1.0, ssig);
    float xs[4] = {v.x, v.y, v.z, v.w};
    signed char out[4][4];
#pragma unroll
    for (int e = 0; e < 4; ++e) {
        long X = __double2ll_rn((double)xs[e] * s2);
#pragma unroll
        for (int l = 0; l < 3; ++l) {
            int d = (int)(((X + 128) & 255) - 128);
            out[l][e] = (signed char)d;
            X = (X - d) >> 8;
        }
        out[3][e] = (signed char)X;
    }
#pragma unroll
    for (int l = 0; l < 4; ++l)
        *(char4*)&limbs[(size_t)l * plane_stride + (size_t)row * 1024 + tid * 4] =
            *(char4*)&out[l][0];
}

// ---------- fused x prep: int8 limb quantize + bf16 cast (single read of x) ----------
__global__ __launch_bounds__(256) void prep_x(
    const float* __restrict__ src, signed char* __restrict__ limbs,
    long plane_stride, double* __restrict__ scale,
    short* __restrict__ hi)
{
    const int row = blockIdx.x, tid = threadIdx.x;
    const float4 v = ((const float4*)(src + (size_t)row * 1024))[tid];
    float m = fmaxf(fmaxf(fabsf(v.x), fabsf(v.y)), fmaxf(fabsf(v.z), fabsf(v.w)));
#pragma unroll
    for (int off = 32; off > 0; off >>= 1) m = fmaxf(m, __shfl_down(m, off));
    __shared__ float wmax[4];
    __shared__ int ssig;
    if ((tid & 63) == 0) wmax[tid >> 6] = m;
    __syncthreads();
    if (tid == 0) {
        float rm = fmaxf(fmaxf(wmax[0], wmax[1]), fmaxf(wmax[2], wmax[3]));
        int sig = (rm > 0.f) ? (29 - ilogbf(rm)) : 0;
        ssig = sig;
        scale[row] = ldexp(1.0, -sig);
    }
    __syncthreads();
    const double s2 = ldexp(1.0, ssig);
    float xs[4] = {v.x, v.y, v.z, v.w};
    signed char out[4][4];
    __align__(8) short h[4];
#pragma unroll
    for (int e = 0; e < 4; ++e) {
        long X = __double2ll_rn((double)xs[e] * s2);
#pragma unroll
        for (int lmb = 0; lmb < 3; ++lmb) {
            int d = (int)(((X + 128) & 255) - 128);
            out[lmb][e] = (signed char)d;
            X = (X - d) >> 8;
        }
        out[3][e] = (signed char)X;
        h[e] = f2bf(xs[e]);
    }
#pragma unroll
    for (int lmb = 0; lmb < 4; ++lmb)
        *(char4*)&limbs[(size_t)lmb * plane_stride + (size_t)row * 1024 + tid * 4] =
            *(char4*)&out[lmb][0];
    *(short4*)&hi[(size_t)row * 1024 + tid * 4] = *(short4*)h;
}

// ---------- i8-MFMA projection -> fp32 out; 10 pairs (i+j>=3), 4 levels ----------
// gload_lds staging; LDS dest linear, global source pre-swizzled (R6/R8-verified).
__global__ __launch_bounds__(256, 4) void gemm_i8qk(
    const signed char* __restrict__ Xl,
    const signed char* __restrict__ Wql,
    const signed char* __restrict__ Wkl,
    const double* __restrict__ xsc,
    const double* __restrict__ wqsc, const double* __restrict__ wksc,
    const float* __restrict__ bq, const float* __restrict__ bk,
    float* __restrict__ Qf, float* __restrict__ Kf)
{
    const int K = 1024, N = 1024;
    const long MK = 2048L * 1024, NK = 1024L * 1024;
    const signed char* Wl = blockIdx.z ? Wkl : Wql;
    const double* wsc = blockIdx.z ? wksc : wqsc;
    const float* bias = blockIdx.z ? bk : bq;
    float* C = blockIdx.z ? Kf : Qf;

    __shared__ __align__(16) signed char Asm[4][64][64];
    __shared__ __align__(16) signed char Bsm[4][64][64];

    const int tid  = threadIdx.x;
    const int lane = tid & 63, wave = tid >> 6;
    const int wm = wave >> 1, wn = wave & 1;
    const int quad = lane >> 4, l16 = lane & 15;
    const int m0 = blockIdx.y * 64, n0 = blockIdx.x * 64;

    const int srow = tid >> 2;
    const int cswz = ((tid & 3) ^ ((srow >> 1) & 3));
    const signed char* ap = Xl + (size_t)(m0 + srow) * K + cswz * 16;
    const signed char* bp = Wl + (size_t)(n0 + srow) * K + cswz * 16;

    signed char* aw = (signed char*)Asm + (wave << 10);
    signed char* bw = (signed char*)Bsm + (wave << 10);

    i4v acc[4][2][2] = {};   // level s = i+j-3

    for (int k0 = 0; k0 < K; k0 += 64) {
        __syncthreads();
#pragma unroll
        for (int l = 0; l < 4; ++l) {
            g2l16(ap + l * MK + k0, aw + l * 4096);
            g2l16(bp + l * NK + k0, bw + l * 4096);
        }
        __syncthreads();

        i4v bF[4][2];
#pragma unroll
        for (int j = 0; j < 4; ++j)
#pragma unroll
            for (int nt = 0; nt < 2; ++nt) {
                const int R = wn * 32 + nt * 16 + l16;
                bF[j][nt] = *(const i4v*)&Bsm[j][R][(quad ^ ((R >> 1) & 3)) * 16];
            }

#pragma unroll
        for (int i = 0; i < 4; ++i) {
            const int R0 = wm * 32 + l16;
            const int R1 = wm * 32 + 16 + l16;
            i4v a0 = *(const i4v*)&Asm[i][R0][(quad ^ ((R0 >> 1) & 3)) * 16];
            i4v a1 = *(const i4v*)&Asm[i][R1][(quad ^ ((R1 >> 1) & 3)) * 16];
#pragma unroll
            for (int j = 0; j < 4; ++j) {
                if (i + j < 3) continue;
                const int s = i + j - 3;
                acc[s][0][0] = __builtin_amdgcn_mfma_i32_16x16x64_i8(a0, bF[j][0], acc[s][0][0], 0, 0, 0);
                acc[s][0][1] = __builtin_amdgcn_mfma_i32_16x16x64_i8(a0, bF[j][1], acc[s][0][1], 0, 0, 0);
                acc[s][1][0] = __builtin_amdgcn_mfma_i32_16x16x64_i8(a1, bF[j][0], acc[s][1][0], 0, 0, 0);
                acc[s][1][1] = __builtin_amdgcn_mfma_i32_16x16x64_i8(a1, bF[j][1], acc[s][1][1], 0, 0, 0);
            }
        }
    }

    const double wt0 = ldexp(1.0, 24), wt1 = ldexp(1.0, 32);
    const double wt2 = ldexp(1.0, 40), wt3 = ldexp(1.0, 48);
#pragma unroll
    for (int mt = 0; mt < 2; ++mt)
#pragma unroll
        for (int nt = 0; nt < 2; ++nt)
#pragma unroll
            for (int r = 0; r < 4; ++r) {
                int row = m0 + wm * 32 + mt * 16 + quad * 4 + r;
                int col = n0 + wn * 32 + nt * 16 + l16;
                double dsum = wt0 * (double)acc[0][mt][nt][r]
                            + wt1 * (double)acc[1][mt][nt][r]
                            + wt2 * (double)acc[2][mt][nt][r]
                            + wt3 * (double)acc[3][mt][nt][r];
                C[(size_t)row * N + col] =
                    (float)(dsum * xsc[row] * wsc[col] + (double)bias[col]);
            }
}

// ------- V projection, pure bf16 single-MFMA; gload_lds staging + swizzle -------
__global__ __launch_bounds__(256, 4) void gemm_v64(
    const short* __restrict__ Ahp, const short* __restrict__ Bhp,
    const float* __restrict__ bias, float* __restrict__ C)
{
    const int K = 1024, N = 1024;
    __shared__ __align__(16) short Ah[64][32];
    __shared__ __align__(16) short Bh[64][32];

    const int tid = threadIdx.x, lane = tid & 63, wave = tid >> 6;
    const int wm = wave >> 1, wn = wave & 1;
    const int quad = lane >> 4, l16 = lane & 15;
    const int m0 = blockIdx.y * 64, n0 = blockIdx.x * 64;
    const int srow = tid >> 2;
    const int cswz = ((tid & 3) ^ ((srow >> 1) & 3));
    const char* ap = (const char*)(Ahp + (size_t)(m0 + srow) * K) + cswz * 16;
    const char* bp = (const char*)(Bhp + (size_t)(n0 + srow) * K) + cswz * 16;
    char* aw = (char*)Ah + (wave << 10);
    char* bw = (char*)Bh + (wave << 10);

    f4 acc[2][2] = {};
    for (int k0 = 0; k0 < K; k0 += 32) {
        __syncthreads();
        g2l16(ap + 2 * k0, aw);
        g2l16(bp + 2 * k0, bw);
        __syncthreads();

        s8v af[2], bf[2];
#pragma unroll
        for (int t = 0; t < 2; ++t) {
            const int Ra = wm * 32 + t * 16 + l16;
            const int Rb = wn * 32 + t * 16 + l16;
            af[t] = *(const s8v*)((const char*)Ah + Ra * 64 + ((quad ^ ((Ra >> 1) & 3)) << 4));
            bf[t] = *(const s8v*)((const char*)Bh + Rb * 64 + ((quad ^ ((Rb >> 1) & 3)) << 4));
        }
#pragma unroll
        for (int mt = 0; mt < 2; ++mt)
#pragma unroll
            for (int nt = 0; nt < 2; ++nt)
                acc[mt][nt] = __builtin_amdgcn_mfma_f32_16x16x32_bf16(
                    af[mt], bf[nt], acc[mt][nt], 0, 0, 0);
    }
#pragma unroll
    for (int mt = 0; mt < 2; ++mt)
#pragma unroll
        for (int nt = 0; nt < 2; ++nt)
#pragma unroll
            for (int r = 0; r < 4; ++r) {
                int row = m0 + wm * 32 + mt * 16 + quad * 4 + r;
                int col = n0 + wn * 32 + nt * 16 + l16;
                C[(size_t)row * N + col] = acc[mt][nt][r] + bias[col];
            }
}

// ------- score GEMM: 64x64 tile, FP16 inputs (noise ~2e-5), fp32 out -------
__global__ __launch_bounds__(256, 4) void gemm_score(
    const short* __restrict__ Qh, const short* __restrict__ Kh,
    float* __restrict__ C)
{
    const int K = 1024, N = 2048;
    __shared__ __align__(16) short As[64][32];
    __shared__ __align__(16) short Bs[64][32];
    const int tid = threadIdx.x, lane = tid & 63, wave = tid >> 6;
    const int wm = wave >> 1, wn = wave & 1;
    const int quad = lane >> 4, l16 = lane & 15;
    const int m0 = blockIdx.y * 64, n0 = blockIdx.x * 64;
    const int srow = tid >> 2;
    const int cswz = ((tid & 3) ^ ((srow >> 1) & 3));
    const char* ap = (const char*)(Qh + (size_t)(m0 + srow) * K) + cswz * 16;
    const char* bp = (const char*)(Kh + (size_t)(n0 + srow) * K) + cswz * 16;
    char* aw = (char*)As + (wave << 10);
    char* bw = (char*)Bs + (wave << 10);

    f4 acc[2][2] = {};
    for (int k0 = 0; k0 < K; k0 += 32) {
        __syncthreads();
        g2l16(ap + 2 * k0, aw);
        g2l16(bp + 2 * k0, bw);
        __syncthreads();

        h8v af[2], bf[2];
#pragma unroll
        for (int t = 0; t < 2; ++t) {
            const int Ra = wm * 32 + t * 16 + l16;
            const int Rb = wn * 32 + t * 16 + l16;
            af[t] = *(const h8v*)((const char*)As + Ra * 64 + ((quad ^ ((Ra >> 1) & 3)) << 4));
            bf[t] = *(const h8v*)((const char*)Bs + Rb * 64 + ((quad ^ ((Rb >> 1) & 3)) << 4));
        }
#pragma unroll
        for (int mt = 0; mt < 2; ++mt)
#pragma unroll
            for (int nt = 0; nt < 2; ++nt)
                acc[mt][nt] = __builtin_amdgcn_mfma_f32_16x16x32_f16(
                    af[mt], bf[nt], acc[mt][nt], 0, 0, 0);
    }
#pragma unroll
    for (int mt = 0; mt < 2; ++mt)
#pragma unroll
        for (int nt = 0; nt < 2; ++nt)
#pragma unroll
            for (int r = 0; r < 4; ++r) {
                int row = m0 + wm * 32 + mt * 16 + quad * 4 + r;
                int col = n0 + wn * 32 + nt * 16 + l16;
                C[(size_t)row * N + col] = acc[mt][nt][r];
            }
}

// ------- fp32 in-place L2 normalize (fp64 norm accumulation) + FP16 copy -------
__global__ __launch_bounds__(256) void l2norm_f32h16(
    float* __restrict__ fq, float* __restrict__ fk,
    short* __restrict__ hq, short* __restrict__ hk)
{
    float* f = blockIdx.y ? fk : fq;
    short* h = blockIdx.y ? hk : hq;
    const int row = blockIdx.x;
    const int tid = threadIdx.x;
    float4* p4 = (float4*)(f + (size_t)row * 1024);
    float4 v = p4[tid];
    double s = (double)v.x * v.x + (double)v.y * v.y
             + (double)v.z * v.z + (double)v.w * v.w;
#pragma unroll
    for (int off = 32; off > 0; off >>= 1) s += __shfl_down(s, off);
    __shared__ double ws[5];
    if ((tid & 63) == 0) ws[tid >> 6] = s;
    __syncthreads();
    if (tid == 0) ws[4] = fmax(sqrt(ws[0] + ws[1] + ws[2] + ws[3]), 1e-12);
    __syncthreads();
    const double inv = 1.0 / ws[4];
    float o0 = (float)(v.x * inv), o1 = (float)(v.y * inv);
    float o2 = (float)(v.z * inv), o3 = (float)(v.w * inv);
    float4 o = make_float4(o0, o1, o2, o3);
    p4[tid] = o;
    __align__(8) _Float16 hv[4] = {(_Float16)o0, (_Float16)o1,
                                   (_Float16)o2, (_Float16)o3};
    *(short4*)&h[(size_t)row * 1024 + tid * 4] = *(short4*)hv;
}

// ------- top-NC selection (register tournament) + fp32-input/fp64-accum rerank
//         + 8-row V prefetch + lane-parallel softmax -------
__global__ __launch_bounds__(256) void topk_route(
    const float*  __restrict__ S,
    const float*  __restrict__ Qf,
    const float*  __restrict__ Kf,
    const float*  __restrict__ Vf,
    float* __restrict__ routes_out,
    float* __restrict__ weights_out,
    float* __restrict__ feat_out,
    int batch)
{
    const int P = 2048, D = 1024;
    __shared__ float  qrow[1024];
    __shared__ float  cval[4 * NC];
    __shared__ int    cidx[4 * NC];
    __shared__ int    sel[NC];
    __shared__ double cscore[NC];
    __shared__ int    topi_s[8];
    __shared__ float  wts[8];

    const int p = blockIdx.x;
    const int tid = threadIdx.x;
    const int lane = tid & 63, wave = tid >> 6;

    const float4* sr4 = (const float4*)(S + (size_t)p * P);
    const float4 s0 = sr4[tid];
    const float4 s1 = sr4[tid + 256];
    ((float4*)qrow)[tid] = ((const float4*)(Qf + (size_t)p * D))[tid];

    float v[8] = {s0.x, s0.y, s0.z, s0.w, s1.x, s1.y, s1.z, s1.w};
    int   ji[8];
#pragma unroll
    for (int e = 0; e < 8; ++e) {
        ji[e] = (e < 4) ? (4 * tid + e) : (1024 + 4 * tid + (e - 4));
        if (ji[e] == p) v[e] = -1e30f;   // diagonal mask
    }

    float lv = v[0]; int li = ji[0];
#pragma unroll
    for (int e = 1; e < 8; ++e)
        if (v[e] > lv) { lv = v[e]; li = ji[e]; }

    // ---- per-wave top-NC register tournament (no barriers) ----
    float cv_ = -INFINITY; int ci_ = 0x7fffffff;
#pragma unroll 1
    for (int it = 0; it < NC; ++it) {
        float bv = lv; int bi = li;
#pragma unroll
        for (int off = 32; off > 0; off >>= 1) {
            float ov = __shfl_xor(bv, off);
            int   oi = __shfl_xor(bi, off);
            if (ov > bv || (ov == bv && oi < bi)) { bv = ov; bi = oi; }
        }
        if (lane == it) { cv_ = bv; ci_ = bi; }
#pragma unroll
        for (int e = 0; e < 8; ++e)
            if (ji[e] == bi) v[e] = -INFINITY;
        lv = v[0]; li = ji[0];
#pragma unroll
        for (int e = 1; e < 8; ++e)
            if (v[e] > lv) { lv = v[e]; li = ji[e]; }
    }
    if (lane < NC) { cval[wave * NC + lane] = cv_; cidx[wave * NC + lane] = ci_; }
    __syncthreads();

    // ---- rank-based merge 4*NC -> NC on wave 0 ----
    if (wave == 0) {
        float mv = (lane < 4 * NC) ? cval[lane] : -INFINITY;
        int   mi = (lane < 4 * NC) ? cidx[lane] : 0x7fffffff;
        int rank = 0;
#pragma unroll 1
        for (int j = 0; j < 4 * NC; ++j) {
            float vj = __shfl(mv, j);
            int   ij = __shfl(mi, j);
            rank += (vj > mv || (vj == mv && ij < mi)) ? 1 : 0;
        }
        if (lane < 4 * NC && rank < NC) sel[rank] = mi;
    }
    __syncthreads();

    // ---- prefetch first 8 candidate V rows (covers final set ~94% of rows) ----
    float pfv[8];
#pragma unroll
    for (int c = 0; c < 8; ++c)
        pfv[c] = Vf[(size_t)sel[c] * D + tid * 4];

    // ---- rerank: wave w handles candidates w, w+4; waves 0,1 also 8,9 ----
    {
        const float* k0r = Kf + (size_t)sel[wave] * D;
        const float* k1r = Kf + (size_t)sel[wave + 4] * D;
        const float* k2r = Kf + (size_t)sel[8 + (wave & 1)] * D;
        double a0 = 0.0, a1 = 0.0, a2 = 0.0;
#pragma unroll 4
        for (int j = 0; j < 8; ++j) {
            const int e = lane * 2 + j * 128;
            const float2 q2 = *(const float2*)&qrow[e];
            const float2 kA = *(const float2*)&k0r[e];
            const float2 kB = *(const float2*)&k1r[e];
            const float2 kC = *(const float2*)&k2r[e];
            a0 = fma((double)q2.x, (double)kA.x, fma((double)q2.y, (double)kA.y, a0));
            a1 = fma((double)q2.x, (double)kB.x, fma((double)q2.y, (double)kB.y, a1));
            a2 = fma((double)q2.x, (double)kC.x, fma((double)q2.y, (double)kC.y, a2));
        }
#pragma unroll
        for (int off = 32; off > 0; off >>= 1) {
            a0 += __shfl_xor(a0, off);
            a1 += __shfl_xor(a1, off);
            a2 += __shfl_xor(a2, off);
        }
        if (lane == 0) {
            cscore[wave]     = a0;
            cscore[wave + 4] = a1;
            if (wave < 2) cscore[8 + wave] = a2;
        }
    }

    // consume prefetch values (keeps loads live; no output effect)
    {
        float pf = 0.f;
#pragma unroll
        for (int c = 0; c < 8; ++c) pf += pfv[c];
        asm volatile("" :: "v"(pf));
    }
    __syncthreads();

    // ---- lane-parallel top-8 of NC + softmax on wave 0 ----
    if (wave == 0) {
        double sc_ = (lane < NC) ? cscore[lane] : -1.0e308;
        int    id_ = (lane < NC) ? sel[lane]    : 0x7fffffff;
        int rank = 0;
#pragma unroll
        for (int j = 0; j < NC; ++j) {
            double vj = __shfl(sc_, j);
            int    ij = __shfl(id_, j);
            rank += (vj > sc_ || (vj == sc_ && ij < id_)) ? 1 : 0;
        }
        double mm = sc_;
#pragma unroll
        for (int off = 32; off > 0; off >>= 1) mm = fmax(mm, __shfl_xor(mm, off));
        double e = (rank < 8 && lane < NC) ? exp((sc_ - mm) / TEMP) : 0.0;
        double sum = e;
#pragma unroll
        for (int off = 32; off > 0; off >>= 1) sum += __shfl_xor(sum, off);
        if (rank < 8 && lane < NC) {
            float wk = (float)(e / sum);
            wts[rank] = wk; topi_s[rank] = id_;
            const size_t row = (size_t)batch * P + p;
            routes_out[row * 8 + rank]  = (float)id_;
            weights_out[row * 8 + rank] = wk;
        }
    }
    __syncthreads();

    // ---- V gather + weighted sum (rows mostly L2-hot from prefetch) ----
    float4 a = {0.f, 0.f, 0.f, 0.f};
#pragma unroll
    for (int k = 0; k < 8; ++k) {
        const float4 v4 = ((const float4*)(Vf + (size_t)topi_s[k] * D))[tid];
        float wk = wts[k];
        a.x = fmaf(wk, v4.x, a.x);
        a.y = fmaf(wk, v4.y, a.y);
        a.z = fmaf(wk, v4.z, a.z);
        a.w = fmaf(wk, v4.w, a.w);
    }
    ((float4*)(feat_out + ((size_t)batch * P + p) * D))[tid] = a;
}

extern "C" void kernel_launch(void* const* d_in, const int* in_sizes, int n_in,
                              void* d_out, int out_size, void* d_ws, size_t ws_size,
                              hipStream_t stream)
{
    const float* x  = (const float*)d_in[0];  // (4,2049,1024)
    const float* Wq = (const float*)d_in[1];
    const float* bq = (const float*)d_in[2];
    const float* Wk = (const float*)d_in[3];
    const float* bk = (const float*)d_in[4];
    const float* Wv = (const float*)d_in[5];
    const float* bv = (const float*)d_in[6];

    const int B = 4, P = 2048, D = 1024;
    const size_t PD = (size_t)P * D;
    const size_t DD = (size_t)D * D;

    float*  Qf   = (float*)d_ws;              // P*D fp32 (projection, then normalized)
    float*  Kf   = Qf + PD;                   // P*D fp32
    double* xsc  = (double*)(Kf + PD);        // 2048
    double* wqsc = xsc + 2048;                // 1024
    double* wksc = wqsc + 1024;               // 1024
    short*  Qh   = (short*)(wksc + 1024);     // P*D fp16
    short*  Kh   = Qh + PD;
    short*  xh   = Kh + PD;                   // x bf16
    short*  Wvh  = xh + PD;                   // Wv bf16
    float*  Vf   = (float*)(Wvh + DD);        // P*D f32
    float*  Sf   = Vf + PD;                   // P*P f32
    signed char* Xl  = (signed char*)(Sf + (size_t)P * P);  // 4*P*D
    signed char* Wql = Xl + 4 * PD;                          // 4*D*D
    signed char* Wkl = Wql + 4 * DD;

    float* out     = (float*)d_out;
    float* routes  = out;
    float* weights = out + (size_t)B * P * 8;
    float* feat    = out + (size_t)B * P * 16;

    dim3 blk(256);
    prep_w<<<dim3(1024, 3), blk, 0, stream>>>(Wq, Wk, Wv, Wql, Wkl, wqsc, wksc, Wvh);

    for (int b = 0; b < B; ++b) {
        const float* xb = x + ((size_t)b * 2049 + 1) * D;  // rows 1..2048 contiguous
        prep_x<<<dim3(P), blk, 0, stream>>>(xb, Xl, (long)PD, xsc, xh);
        gemm_i8qk<<<dim3(16, 32, 2), blk, 0, stream>>>(Xl, Wql, Wkl, xsc, wqsc, wksc,
                                                       bq, bk, Qf, Kf);
        gemm_v64<<<dim3(16, 32), blk, 0, stream>>>(xh, Wvh, bv, Vf);
        l2norm_f32h16<<<dim3(P, 2), blk, 0, stream>>>(Qf, Kf, Qh, Kh);
        gemm_score<<<dim3(32, 32), blk, 0, stream>>>(Qh, Kh, Sf);
        topk_route<<<dim3(P), blk, 0, stream>>>(Sf, Qf, Kf, Vf, routes, weights, feat, b);
    }
}